// Round 1
// baseline (656.488 us; speedup 1.0000x reference)
//
#include <hip/hip_runtime.h>
#include <hip/hip_bf16.h>

// Problem constants: B=4, C=256, H=W=64, N=4096, Cq=32
#define NB 4
#define NC 256
#define NQ 32
#define NN 4096
#define NO 320   // 32 q + 32 k + 256 v fused output channels

typedef __attribute__((ext_vector_type(4))) float f32x4;
typedef __attribute__((ext_vector_type(8))) short s16x8;

__device__ __forceinline__ void gload_lds16(const void* g, void* l) {
    __builtin_amdgcn_global_load_lds((const __attribute__((address_space(1))) void*)g,
                                     (__attribute__((address_space(3))) void*)l, 16, 0, 0);
}

// ---------------- K1: fused QKV 1x1-conv projection (fp32 VALU) ----------------
// grid (N/64, B), block 512. LDS: x tile [256 c][64 n] fp32 = 64 KB.
// q,k written fp32 (B,32,N); v written bf16 (B,256,N).
__global__ __launch_bounds__(512, 1) void k_proj(
    const float* __restrict__ x,
    const float* __restrict__ Wq, const float* __restrict__ bq,
    const float* __restrict__ Wk, const float* __restrict__ bk,
    const float* __restrict__ Wv, const float* __restrict__ bv,
    float* __restrict__ qo, float* __restrict__ ko, __hip_bfloat16* __restrict__ vo)
{
    __shared__ __align__(16) float xs[NC * 64];
    const int b  = blockIdx.y;
    const int n0 = blockIdx.x * 64;
    const int t  = threadIdx.x;

    // stage x[b, :, n0:n0+64): 4096 float4, 8 per thread, coalesced 256B rows
    {
        const float* xb = x + (size_t)b * NC * NN + n0;
        #pragma unroll
        for (int it = 0; it < 8; ++it) {
            int i4 = t + it * 512;            // 0..4095
            int c  = i4 >> 4;
            int nq = (i4 & 15) << 2;
            float4 v4 = *(const float4*)(xb + (size_t)c * NN + nq);
            *(float4*)&xs[c * 64 + nq] = v4;
        }
    }
    __syncthreads();

    const int g  = t >> 4;            // 0..31 (wave-chunk of 4 o-values per wave)
    const int n4 = (t & 15) << 2;     // 0,4,...,60
    #pragma unroll 1
    for (int j = 0; j < 10; ++j) {
        int o = g + 32 * j;           // 0..319, uniform branch per j
        const float* Wrow; float bias;
        if (o < 32)      { Wrow = Wq + o * NC;        bias = bq[o]; }
        else if (o < 64) { Wrow = Wk + (o - 32) * NC; bias = bk[o - 32]; }
        else             { Wrow = Wv + (o - 64) * NC; bias = bv[o - 64]; }
        float a0 = bias, a1 = bias, a2 = bias, a3 = bias;
        #pragma unroll 8
        for (int c = 0; c < NC; ++c) {
            float w = Wrow[c];
            float4 xv = *(const float4*)&xs[c * 64 + n4];
            a0 += w * xv.x; a1 += w * xv.y; a2 += w * xv.z; a3 += w * xv.w;
        }
        a0 = fmaxf(a0, 0.f); a1 = fmaxf(a1, 0.f);
        a2 = fmaxf(a2, 0.f); a3 = fmaxf(a3, 0.f);
        int nn = n0 + n4;
        if (o < 32) {
            *(float4*)(qo + ((size_t)b * NQ + o) * NN + nn) = make_float4(a0, a1, a2, a3);
        } else if (o < 64) {
            *(float4*)(ko + ((size_t)b * NQ + (o - 32)) * NN + nn) = make_float4(a0, a1, a2, a3);
        } else {
            union { __hip_bfloat16 h[4]; unsigned long long u; } pk;
            pk.h[0] = __float2bfloat16(a0); pk.h[1] = __float2bfloat16(a1);
            pk.h[2] = __float2bfloat16(a2); pk.h[3] = __float2bfloat16(a3);
            *(unsigned long long*)(vo + ((size_t)b * NC + (o - 64)) * NN + nn) = pk.u;
        }
    }
}

// ---------------- K2: energy (q^T k, K=32) + row softmax, fused ----------------
// grid (N/4, B), block 256 = 4 waves; one wave per attention row.
// Energy row lives in LDS (4 rows x 16 KB = 64 KB); single normalized write.
__global__ __launch_bounds__(256, 1) void k_attn(
    const float* __restrict__ q, const float* __restrict__ k,
    float* __restrict__ att)
{
    __shared__ float es[4][NN];
    const int b    = blockIdx.y;
    const int t    = threadIdx.x;
    const int wv   = t >> 6;
    const int lane = t & 63;
    const int n    = blockIdx.x * 4 + wv;

    // broadcast-load this row's q column (32 values)
    const float* qb = q + (size_t)b * NQ * NN + n;
    float qv[32];
    #pragma unroll
    for (int c = 0; c < 32; ++c) qv[c] = qb[(size_t)c * NN];

    const float* kb = k + (size_t)b * NQ * NN;
    float mx = -3.0e38f;
    for (int i = 0; i < 64; ++i) {
        int m = i * 64 + lane;
        float acc = 0.f;
        #pragma unroll
        for (int c = 0; c < 32; ++c) acc += qv[c] * kb[(size_t)c * NN + m];
        es[wv][m] = acc;
        mx = fmaxf(mx, acc);
    }
    #pragma unroll
    for (int off = 32; off; off >>= 1) mx = fmaxf(mx, __shfl_xor(mx, off));
    float s = 0.f;
    for (int i = 0; i < 64; ++i) {
        int m = i * 64 + lane;
        float p = __expf(es[wv][m] - mx);
        es[wv][m] = p;
        s += p;
    }
    #pragma unroll
    for (int off = 32; off; off >>= 1) s += __shfl_xor(s, off);
    const float inv = 1.f / s;
    float* arow = att + ((size_t)b * NN + n) * NN;
    for (int i = 0; i < 64; ++i) {
        int m = i * 64 + lane;
        arow[m] = es[wv][m] * inv;
    }
}

// ---------------- K3: out = gamma * (v @ att^T) + x via bf16 MFMA ----------------
// Per batch GEMM: M=C=256, N=4096 (n), K=4096 (m).
// grid (N/64, B), block 256 = 4 waves; wave w owns c-rows [64w,64w+64), 64 n-cols.
// A = v bf16 [c][m] (K-contiguous) via global_load_lds; B = att fp32 -> bf16 reg-staged.
__global__ __launch_bounds__(256, 1) void k_out(
    const __hip_bfloat16* __restrict__ v, const float* __restrict__ att,
    const float* __restrict__ x, const float* __restrict__ gamma,
    float* __restrict__ out)
{
    __shared__ __align__(16) __hip_bfloat16 As[NC * 32];  // 16 KB: v tile [256][32]
    __shared__ __align__(16) __hip_bfloat16 Bs[64 * 32];  //  4 KB: att tile [64 n][32 m]
    const int b    = blockIdx.y;
    const int n0   = blockIdx.x * 64;
    const int t    = threadIdx.x;
    const int wv   = t >> 6;
    const int lane = t & 63;

    const __hip_bfloat16* vb = v + (size_t)b * NC * NN;
    const float* attb = att + ((size_t)b * NN + n0) * NN;

    f32x4 acc[4][4] = {};

    for (int m0 = 0; m0 < NN; m0 += 32) {
        // stage A (v tile): 1024 x 16B chunks, 4 global_load_lds per thread
        #pragma unroll
        for (int jj = 0; jj < 4; ++jj) {
            int s   = jj * 256 + t;        // 0..1023: row = s/4, 16B-chunk = s%4
            int row = s >> 2, ch = s & 3;
            const __hip_bfloat16* gp = vb + (size_t)row * NN + m0 + ch * 8;
            int sbase = jj * 256 + wv * 64;  // wave-uniform LDS base (lane*16 added by HW)
            gload_lds16((const void*)gp, (void*)((char*)As + (size_t)sbase * 16));
        }
        // stage B (att tile, fp32 -> bf16): 512 float4 slots, 2 per thread
        #pragma unroll
        for (int jj = 0; jj < 2; ++jj) {
            int s  = jj * 256 + t;         // 0..511: n-row = s/8, float4 = s%8
            int nr = s >> 3, f4 = s & 7;
            float4 w = *(const float4*)(attb + (size_t)nr * NN + m0 + f4 * 4);
            union { __hip_bfloat16 h[4]; unsigned long long u; } pk;
            pk.h[0] = __float2bfloat16(w.x); pk.h[1] = __float2bfloat16(w.y);
            pk.h[2] = __float2bfloat16(w.z); pk.h[3] = __float2bfloat16(w.w);
            *(unsigned long long*)&Bs[s * 4] = pk.u;
        }
        __syncthreads();

        const int r = lane & 15, kb8 = (lane >> 4) * 8;
        s16x8 af[4], bfr[4];
        #pragma unroll
        for (int ci = 0; ci < 4; ++ci)
            af[ci] = *(const s16x8*)&As[(wv * 64 + ci * 16 + r) * 32 + kb8];
        #pragma unroll
        for (int ni = 0; ni < 4; ++ni)
            bfr[ni] = *(const s16x8*)&Bs[(ni * 16 + r) * 32 + kb8];
        #pragma unroll
        for (int ci = 0; ci < 4; ++ci)
            #pragma unroll
            for (int ni = 0; ni < 4; ++ni)
                acc[ci][ni] = __builtin_amdgcn_mfma_f32_16x16x32_bf16(
                    af[ci], bfr[ni], acc[ci][ni], 0, 0, 0);
        __syncthreads();
    }

    // epilogue: out[b][c][n] = gamma*acc + x  (C/D: col=lane&15, row=(lane>>4)*4+j)
    const float gm = gamma[0];
    #pragma unroll
    for (int ci = 0; ci < 4; ++ci) {
        #pragma unroll
        for (int ni = 0; ni < 4; ++ni) {
            #pragma unroll
            for (int jr = 0; jr < 4; ++jr) {
                int c  = wv * 64 + ci * 16 + (lane >> 4) * 4 + jr;
                int nn = n0 + ni * 16 + (lane & 15);
                size_t idx = ((size_t)b * NC + c) * NN + nn;
                out[idx] = gm * acc[ci][ni][jr] + x[idx];
            }
        }
    }
}

extern "C" void kernel_launch(void* const* d_in, const int* in_sizes, int n_in,
                              void* d_out, int out_size, void* d_ws, size_t ws_size,
                              hipStream_t stream) {
    const float* x     = (const float*)d_in[0];
    const float* Wq    = (const float*)d_in[1];
    const float* bq    = (const float*)d_in[2];
    const float* Wk    = (const float*)d_in[3];
    const float* bk    = (const float*)d_in[4];
    const float* Wv    = (const float*)d_in[5];
    const float* bv    = (const float*)d_in[6];
    const float* gamma = (const float*)d_in[7];

    float* out = (float*)d_out;
    float* att = out + (size_t)NB * NC * NN;   // attention output region (268 MB)

    // workspace layout: q fp32 (2 MB) | k fp32 (2 MB) | v bf16 (8.4 MB)
    float* qo = (float*)d_ws;
    float* ko = qo + (size_t)NB * NQ * NN;
    __hip_bfloat16* vo = (__hip_bfloat16*)(ko + (size_t)NB * NQ * NN);

    k_proj<<<dim3(NN / 64, NB), 512, 0, stream>>>(x, Wq, bq, Wk, bk, Wv, bv, qo, ko, vo);
    k_attn<<<dim3(NN / 4, NB), 256, 0, stream>>>(qo, ko, att);
    k_out <<<dim3(NN / 64, NB), 256, 0, stream>>>(vo, att, x, gamma, out);
}

// Round 2
// 339.716 us; speedup vs baseline: 1.9325x; 1.9325x over previous
//
#include <hip/hip_runtime.h>
#include <hip/hip_bf16.h>

// Problem constants: B=4, C=256, H=W=64, N=4096, Cq=32
#define NB 4
#define NC 256
#define NQ 32
#define NN 4096

typedef __attribute__((ext_vector_type(4))) float f32x4;
typedef __attribute__((ext_vector_type(8))) short s16x8;

__device__ __forceinline__ void gload_lds16(const void* g, void* l) {
    __builtin_amdgcn_global_load_lds((const __attribute__((address_space(1))) void*)g,
                                     (__attribute__((address_space(3))) void*)l, 16, 0, 0);
}

// ---------------- K1: fused QKV 1x1-conv projection (fp32 VALU) ----------------
// grid (N/64, B), block 512. LDS: x tile [256 c][64 n] fp32 = 64 KB.
// q,k written as bf16 hi/lo pairs in [n][32] layout (MFMA-fragment-ready);
// v written bf16 [c][m].
__global__ __launch_bounds__(512, 1) void k_proj(
    const float* __restrict__ x,
    const float* __restrict__ Wq, const float* __restrict__ bq,
    const float* __restrict__ Wk, const float* __restrict__ bk,
    const float* __restrict__ Wv, const float* __restrict__ bv,
    __hip_bfloat16* __restrict__ qh, __hip_bfloat16* __restrict__ ql,
    __hip_bfloat16* __restrict__ kh, __hip_bfloat16* __restrict__ kl,
    __hip_bfloat16* __restrict__ vo)
{
    __shared__ __align__(16) float xs[NC * 64];
    const int b  = blockIdx.y;
    const int n0 = blockIdx.x * 64;
    const int t  = threadIdx.x;

    {
        const float* xb = x + (size_t)b * NC * NN + n0;
        #pragma unroll
        for (int it = 0; it < 8; ++it) {
            int i4 = t + it * 512;
            int c  = i4 >> 4;
            int nq = (i4 & 15) << 2;
            float4 v4 = *(const float4*)(xb + (size_t)c * NN + nq);
            *(float4*)&xs[c * 64 + nq] = v4;
        }
    }
    __syncthreads();

    const int g  = t >> 4;            // 0..31
    const int n4 = (t & 15) << 2;     // 0,4,...,60
    #pragma unroll 1
    for (int j = 0; j < 10; ++j) {
        int o = g + 32 * j;           // 0..319
        const float* Wrow; float bias;
        if (o < 32)      { Wrow = Wq + o * NC;        bias = bq[o]; }
        else if (o < 64) { Wrow = Wk + (o - 32) * NC; bias = bk[o - 32]; }
        else             { Wrow = Wv + (o - 64) * NC; bias = bv[o - 64]; }
        float a0 = bias, a1 = bias, a2 = bias, a3 = bias;
        #pragma unroll 8
        for (int c = 0; c < NC; ++c) {
            float w = Wrow[c];
            float4 xv = *(const float4*)&xs[c * 64 + n4];
            a0 += w * xv.x; a1 += w * xv.y; a2 += w * xv.z; a3 += w * xv.w;
        }
        a0 = fmaxf(a0, 0.f); a1 = fmaxf(a1, 0.f);
        a2 = fmaxf(a2, 0.f); a3 = fmaxf(a3, 0.f);
        int nn = n0 + n4;
        if (o < 64) {
            // q or k: split into bf16 hi/lo, store transposed [n][32]
            __hip_bfloat16 *dh, *dl; int c;
            if (o < 32) { dh = qh; dl = ql; c = o; }
            else        { dh = kh; dl = kl; c = o - 32; }
            float vals[4] = {a0, a1, a2, a3};
            #pragma unroll
            for (int i = 0; i < 4; ++i) {
                float vv = vals[i];
                __hip_bfloat16 h = __float2bfloat16(vv);
                float lo = vv - __bfloat162float(h);
                size_t base = ((size_t)b * NN + nn + i) * NQ + c;
                dh[base] = h;
                dl[base] = __float2bfloat16(lo);
            }
        } else {
            union { __hip_bfloat16 h[4]; unsigned long long u; } pk;
            pk.h[0] = __float2bfloat16(a0); pk.h[1] = __float2bfloat16(a1);
            pk.h[2] = __float2bfloat16(a2); pk.h[3] = __float2bfloat16(a3);
            *(unsigned long long*)(vo + ((size_t)b * NC + (o - 64)) * NN + nn) = pk.u;
        }
    }
}

// ---------------- K2: energy via MFMA (split-bf16) + 2-pass online softmax ----------------
// grid (N/64, B) = 256 blocks, block 512 = 8 waves. Block owns 64 rows (n),
// waves split the m axis 8-way (512 m = 32 tiles of 16 each).
// Pass 1: online (max, sum-exp) per row. Cross-lane + cross-wave combine.
// Pass 2: recompute e-tiles, write normalized attention (268 MB, the BW floor).
#define WPB 8
#define MTW (NN / 16 / WPB)   // 32 m-tiles per wave

__global__ __launch_bounds__(512, 1) void k_attn2(
    const __hip_bfloat16* __restrict__ qh, const __hip_bfloat16* __restrict__ ql,
    const __hip_bfloat16* __restrict__ kh, const __hip_bfloat16* __restrict__ kl,
    float* __restrict__ att)
{
    __shared__ float redM[WPB][64];
    __shared__ float redS[WPB][64];
    __shared__ float finM[64], finI[64];

    const int b = blockIdx.y, n0 = blockIdx.x * 64;
    const int t = threadIdx.x, wv = t >> 6, lane = t & 63;
    const int r = lane & 15, kc = (lane >> 4) * 8;

    // A fragments (q), loaded once: 4 n-tiles x (hi,lo)
    const __hip_bfloat16* qhb = qh + ((size_t)b * NN + n0) * NQ;
    const __hip_bfloat16* qlb = ql + ((size_t)b * NN + n0) * NQ;
    s16x8 afh[4], afl[4];
    #pragma unroll
    for (int nt = 0; nt < 4; ++nt) {
        afh[nt] = *(const s16x8*)(qhb + (size_t)(nt * 16 + r) * NQ + kc);
        afl[nt] = *(const s16x8*)(qlb + (size_t)(nt * 16 + r) * NQ + kc);
    }
    const __hip_bfloat16* khb = kh + (size_t)b * NN * NQ;
    const __hip_bfloat16* klb = kl + (size_t)b * NN * NQ;

    const int m0 = wv * (NN / WPB);   // this wave's m range start

    float rm[4][4], rs[4][4];
    #pragma unroll
    for (int nt = 0; nt < 4; ++nt)
        #pragma unroll
        for (int j = 0; j < 4; ++j) { rm[nt][j] = -3.0e38f; rs[nt][j] = 0.f; }

    // ---- pass 1 ----
    s16x8 bh = *(const s16x8*)(khb + (size_t)(m0 + r) * NQ + kc);
    s16x8 bl = *(const s16x8*)(klb + (size_t)(m0 + r) * NQ + kc);
    #pragma unroll 1
    for (int mt = 0; mt < MTW; ++mt) {
        s16x8 cbh = bh, cbl = bl;
        if (mt + 1 < MTW) {
            int m = m0 + (mt + 1) * 16;
            bh = *(const s16x8*)(khb + (size_t)(m + r) * NQ + kc);
            bl = *(const s16x8*)(klb + (size_t)(m + r) * NQ + kc);
        }
        #pragma unroll
        for (int nt = 0; nt < 4; ++nt) {
            f32x4 acc = {0.f, 0.f, 0.f, 0.f};
            acc = __builtin_amdgcn_mfma_f32_16x16x32_bf16(afh[nt], cbh, acc, 0, 0, 0);
            acc = __builtin_amdgcn_mfma_f32_16x16x32_bf16(afh[nt], cbl, acc, 0, 0, 0);
            acc = __builtin_amdgcn_mfma_f32_16x16x32_bf16(afl[nt], cbh, acc, 0, 0, 0);
            #pragma unroll
            for (int j = 0; j < 4; ++j) {
                float v  = acc[j];
                float nm = fmaxf(rm[nt][j], v);
                rs[nt][j] = rs[nt][j] * __expf(rm[nt][j] - nm) + __expf(v - nm);
                rm[nt][j] = nm;
            }
        }
    }
    // reduce across the 16 m-columns held by lanes sharing a row
    #pragma unroll
    for (int nt = 0; nt < 4; ++nt) {
        #pragma unroll
        for (int j = 0; j < 4; ++j) {
            float M = rm[nt][j], S = rs[nt][j];
            #pragma unroll
            for (int off = 1; off < 16; off <<= 1) {
                float M2 = __shfl_xor(M, off), S2 = __shfl_xor(S, off);
                float nm = fmaxf(M, M2);
                S = S * __expf(M - nm) + S2 * __expf(M2 - nm);
                M = nm;
            }
            if (r == 0) {
                int row = nt * 16 + (lane >> 4) * 4 + j;
                redM[wv][row] = M; redS[wv][row] = S;
            }
        }
    }
    __syncthreads();
    if (t < 64) {
        float M = -3.0e38f;
        #pragma unroll
        for (int w = 0; w < WPB; ++w) M = fmaxf(M, redM[w][t]);
        float S = 0.f;
        #pragma unroll
        for (int w = 0; w < WPB; ++w) S += redS[w][t] * __expf(redM[w][t] - M);
        finM[t] = M; finI[t] = 1.0f / S;
    }
    __syncthreads();

    float fM[4][4], fI[4][4];
    #pragma unroll
    for (int nt = 0; nt < 4; ++nt)
        #pragma unroll
        for (int j = 0; j < 4; ++j) {
            int row = nt * 16 + (lane >> 4) * 4 + j;
            fM[nt][j] = finM[row]; fI[nt][j] = finI[row];
        }

    // ---- pass 2: recompute + normalized write ----
    float* ab = att + ((size_t)b * NN + n0) * NN;
    bh = *(const s16x8*)(khb + (size_t)(m0 + r) * NQ + kc);
    bl = *(const s16x8*)(klb + (size_t)(m0 + r) * NQ + kc);
    #pragma unroll 1
    for (int mt = 0; mt < MTW; ++mt) {
        s16x8 cbh = bh, cbl = bl;
        if (mt + 1 < MTW) {
            int m = m0 + (mt + 1) * 16;
            bh = *(const s16x8*)(khb + (size_t)(m + r) * NQ + kc);
            bl = *(const s16x8*)(klb + (size_t)(m + r) * NQ + kc);
        }
        int mm = m0 + mt * 16 + r;
        #pragma unroll
        for (int nt = 0; nt < 4; ++nt) {
            f32x4 acc = {0.f, 0.f, 0.f, 0.f};
            acc = __builtin_amdgcn_mfma_f32_16x16x32_bf16(afh[nt], cbh, acc, 0, 0, 0);
            acc = __builtin_amdgcn_mfma_f32_16x16x32_bf16(afh[nt], cbl, acc, 0, 0, 0);
            acc = __builtin_amdgcn_mfma_f32_16x16x32_bf16(afl[nt], cbh, acc, 0, 0, 0);
            #pragma unroll
            for (int j = 0; j < 4; ++j) {
                int row = nt * 16 + (lane >> 4) * 4 + j;
                ab[(size_t)row * NN + mm] = __expf(acc[j] - fM[nt][j]) * fI[nt][j];
            }
        }
    }
}

// ---------------- K3: out = gamma * (v @ att^T) + x via bf16 MFMA ----------------
__global__ __launch_bounds__(256, 1) void k_out(
    const __hip_bfloat16* __restrict__ v, const float* __restrict__ att,
    const float* __restrict__ x, const float* __restrict__ gamma,
    float* __restrict__ out)
{
    __shared__ __align__(16) __hip_bfloat16 As[NC * 32];  // 16 KB: v tile [256][32]
    __shared__ __align__(16) __hip_bfloat16 Bs[64 * 32];  //  4 KB: att tile [64 n][32 m]
    const int b    = blockIdx.y;
    const int n0   = blockIdx.x * 64;
    const int t    = threadIdx.x;
    const int wv   = t >> 6;
    const int lane = t & 63;

    const __hip_bfloat16* vb = v + (size_t)b * NC * NN;
    const float* attb = att + ((size_t)b * NN + n0) * NN;

    f32x4 acc[4][4] = {};

    for (int m0 = 0; m0 < NN; m0 += 32) {
        #pragma unroll
        for (int jj = 0; jj < 4; ++jj) {
            int s   = jj * 256 + t;
            int row = s >> 2, ch = s & 3;
            const __hip_bfloat16* gp = vb + (size_t)row * NN + m0 + ch * 8;
            int sbase = jj * 256 + wv * 64;
            gload_lds16((const void*)gp, (void*)((char*)As + (size_t)sbase * 16));
        }
        #pragma unroll
        for (int jj = 0; jj < 2; ++jj) {
            int s  = jj * 256 + t;
            int nr = s >> 3, f4 = s & 7;
            float4 w = *(const float4*)(attb + (size_t)nr * NN + m0 + f4 * 4);
            union { __hip_bfloat16 h[4]; unsigned long long u; } pk;
            pk.h[0] = __float2bfloat16(w.x); pk.h[1] = __float2bfloat16(w.y);
            pk.h[2] = __float2bfloat16(w.z); pk.h[3] = __float2bfloat16(w.w);
            *(unsigned long long*)&Bs[s * 4] = pk.u;
        }
        __syncthreads();

        const int r = lane & 15, kb8 = (lane >> 4) * 8;
        s16x8 af[4], bfr[4];
        #pragma unroll
        for (int ci = 0; ci < 4; ++ci)
            af[ci] = *(const s16x8*)&As[(wv * 64 + ci * 16 + r) * 32 + kb8];
        #pragma unroll
        for (int ni = 0; ni < 4; ++ni)
            bfr[ni] = *(const s16x8*)&Bs[(ni * 16 + r) * 32 + kb8];
        #pragma unroll
        for (int ci = 0; ci < 4; ++ci)
            #pragma unroll
            for (int ni = 0; ni < 4; ++ni)
                acc[ci][ni] = __builtin_amdgcn_mfma_f32_16x16x32_bf16(
                    af[ci], bfr[ni], acc[ci][ni], 0, 0, 0);
        __syncthreads();
    }

    const float gm = gamma[0];
    #pragma unroll
    for (int ci = 0; ci < 4; ++ci) {
        #pragma unroll
        for (int ni = 0; ni < 4; ++ni) {
            #pragma unroll
            for (int jr = 0; jr < 4; ++jr) {
                int c  = wv * 64 + ci * 16 + (lane >> 4) * 4 + jr;
                int nn = n0 + ni * 16 + (lane & 15);
                size_t idx = ((size_t)b * NC + c) * NN + nn;
                out[idx] = gm * acc[ci][ni][jr] + x[idx];
            }
        }
    }
}

extern "C" void kernel_launch(void* const* d_in, const int* in_sizes, int n_in,
                              void* d_out, int out_size, void* d_ws, size_t ws_size,
                              hipStream_t stream) {
    const float* x     = (const float*)d_in[0];
    const float* Wq    = (const float*)d_in[1];
    const float* bq    = (const float*)d_in[2];
    const float* Wk    = (const float*)d_in[3];
    const float* bk    = (const float*)d_in[4];
    const float* Wv    = (const float*)d_in[5];
    const float* bv    = (const float*)d_in[6];
    const float* gamma = (const float*)d_in[7];

    float* out = (float*)d_out;
    float* att = out + (size_t)NB * NC * NN;   // attention output region (268 MB)

    // workspace: qh | ql | kh | kl (each B*N*32 bf16 = 1 MB) | v bf16 (8 MB)
    const size_t qk_elems = (size_t)NB * NN * NQ;
    __hip_bfloat16* qh = (__hip_bfloat16*)d_ws;
    __hip_bfloat16* ql = qh + qk_elems;
    __hip_bfloat16* kh = ql + qk_elems;
    __hip_bfloat16* kl = kh + qk_elems;
    __hip_bfloat16* vo = kl + qk_elems;

    k_proj <<<dim3(NN / 64, NB), 512, 0, stream>>>(x, Wq, bq, Wk, bk, Wv, bv,
                                                   qh, ql, kh, kl, vo);
    k_attn2<<<dim3(NN / 64, NB), 512, 0, stream>>>(qh, ql, kh, kl, att);
    k_out  <<<dim3(NN / 64, NB), 256, 0, stream>>>(vo, att, x, gamma, out);
}

// Round 3
// 272.171 us; speedup vs baseline: 2.4120x; 1.2482x over previous
//
#include <hip/hip_runtime.h>
#include <hip/hip_bf16.h>

// Problem constants: B=4, C=256, H=W=64, N=4096, Cq=32
#define NB 4
#define NC 256
#define NQ 32
#define NN 4096

typedef __attribute__((ext_vector_type(4))) float f32x4;
typedef __attribute__((ext_vector_type(8))) short s16x8;

__device__ __forceinline__ void gload_lds16(const void* g, void* l) {
    __builtin_amdgcn_global_load_lds((const __attribute__((address_space(1))) void*)g,
                                     (__attribute__((address_space(3))) void*)l, 16, 0, 0);
}
__device__ __forceinline__ float bf2f(short s) {
    return __uint_as_float(((unsigned int)(unsigned short)s) << 16);
}
#define MFMA16(a, b, c) __builtin_amdgcn_mfma_f32_16x16x32_bf16((a), (b), (c), 0, 0, 0)

// ---------------- K1: fused QKV 1x1-conv projection (fp32 VALU) ----------------
// grid (N/64, B), block 512. LDS: x tile [256 c][64 n] fp32 = 64 KB.
// q,k written as bf16 hi/lo pairs in [n][32] layout (MFMA-fragment-ready);
// v written bf16 [c][m].
__global__ __launch_bounds__(512, 1) void k_proj(
    const float* __restrict__ x,
    const float* __restrict__ Wq, const float* __restrict__ bq,
    const float* __restrict__ Wk, const float* __restrict__ bk,
    const float* __restrict__ Wv, const float* __restrict__ bv,
    __hip_bfloat16* __restrict__ qh, __hip_bfloat16* __restrict__ ql,
    __hip_bfloat16* __restrict__ kh, __hip_bfloat16* __restrict__ kl,
    __hip_bfloat16* __restrict__ vo)
{
    __shared__ __align__(16) float xs[NC * 64];
    const int b  = blockIdx.y;
    const int n0 = blockIdx.x * 64;
    const int t  = threadIdx.x;

    {
        const float* xb = x + (size_t)b * NC * NN + n0;
        #pragma unroll
        for (int it = 0; it < 8; ++it) {
            int i4 = t + it * 512;
            int c  = i4 >> 4;
            int nq = (i4 & 15) << 2;
            float4 v4 = *(const float4*)(xb + (size_t)c * NN + nq);
            *(float4*)&xs[c * 64 + nq] = v4;
        }
    }
    __syncthreads();

    const int g  = t >> 4;            // 0..31
    const int n4 = (t & 15) << 2;     // 0,4,...,60
    #pragma unroll 1
    for (int j = 0; j < 10; ++j) {
        int o = g + 32 * j;           // 0..319
        const float* Wrow; float bias;
        if (o < 32)      { Wrow = Wq + o * NC;        bias = bq[o]; }
        else if (o < 64) { Wrow = Wk + (o - 32) * NC; bias = bk[o - 32]; }
        else             { Wrow = Wv + (o - 64) * NC; bias = bv[o - 64]; }
        float a0 = bias, a1 = bias, a2 = bias, a3 = bias;
        #pragma unroll 8
        for (int c = 0; c < NC; ++c) {
            float w = Wrow[c];
            float4 xv = *(const float4*)&xs[c * 64 + n4];
            a0 += w * xv.x; a1 += w * xv.y; a2 += w * xv.z; a3 += w * xv.w;
        }
        a0 = fmaxf(a0, 0.f); a1 = fmaxf(a1, 0.f);
        a2 = fmaxf(a2, 0.f); a3 = fmaxf(a3, 0.f);
        int nn = n0 + n4;
        if (o < 64) {
            __hip_bfloat16 *dh, *dl; int c;
            if (o < 32) { dh = qh; dl = ql; c = o; }
            else        { dh = kh; dl = kl; c = o - 32; }
            float vals[4] = {a0, a1, a2, a3};
            #pragma unroll
            for (int i = 0; i < 4; ++i) {
                float vv = vals[i];
                __hip_bfloat16 h = __float2bfloat16(vv);
                float lo = vv - __bfloat162float(h);
                size_t base = ((size_t)b * NN + nn + i) * NQ + c;
                dh[base] = h;
                dl[base] = __float2bfloat16(lo);
            }
        } else {
            union { __hip_bfloat16 h[4]; unsigned long long u; } pk;
            pk.h[0] = __float2bfloat16(a0); pk.h[1] = __float2bfloat16(a1);
            pk.h[2] = __float2bfloat16(a2); pk.h[3] = __float2bfloat16(a3);
            *(unsigned long long*)(vo + ((size_t)b * NC + (o - 64)) * NN + nn) = pk.u;
        }
    }
}

// ---------------- K2: fused energy + softmax + att-write + PV + epilogue ----------------
// grid (N/64, B), block 256 = 4 waves. Wave owns 16 n-rows fully (all m).
// Pass 1: online (max, sumexp) per row, k frags from global (L2), no barriers.
// Pass 2: recompute QK tile -> exp*inv -> bf16 P in per-wave LDS -> read as
// B-fragment -> att write (2x float4 NT stores) + 16 PV MFMAs vs LDS-staged v
// (double-buffered global_load_lds, 1 barrier/step). Epilogue out = g*acc + x.
__global__ __launch_bounds__(256, 1) void k_fused(
    const __hip_bfloat16* __restrict__ qh, const __hip_bfloat16* __restrict__ ql,
    const __hip_bfloat16* __restrict__ kh, const __hip_bfloat16* __restrict__ kl,
    const __hip_bfloat16* __restrict__ v,
    const float* __restrict__ x, const float* __restrict__ gamma,
    float* __restrict__ out, float* __restrict__ att)
{
    __shared__ __align__(16) __hip_bfloat16 vs[2][NC * 32];  // 2 x 16 KB v tiles
    __shared__ __align__(16) __hip_bfloat16 ps[4][16 * 32];  // per-wave P tile (1 KB)

    const int b  = blockIdx.y, n0 = blockIdx.x * 64;
    const int t  = threadIdx.x, wv = t >> 6, lane = t & 63;
    const int r  = lane & 15, hi = lane >> 4, kc = hi * 8;
    const int nw = n0 + wv * 16;          // wave's first n-row

    const __hip_bfloat16* khb = kh + (size_t)b * NN * NQ;
    const __hip_bfloat16* klb = kl + (size_t)b * NN * NQ;
    const __hip_bfloat16* vb  = v  + (size_t)b * NC * NN;

    // stage v tile 0 early (lands during pass 1)
    #pragma unroll
    for (int jj = 0; jj < 4; ++jj) {
        int s = jj * 256 + t, row = s >> 2, ch = s & 3;
        gload_lds16(vb + (size_t)row * NN + ch * 8,
                    (char*)&vs[0][0] + (size_t)(jj * 256 + wv * 64) * 16);
    }

    // q fragments for this wave's 16 rows
    s16x8 aqh = *(const s16x8*)(qh + ((size_t)b * NN + nw + r) * NQ + kc);
    s16x8 aql = *(const s16x8*)(ql + ((size_t)b * NN + nw + r) * NQ + kc);

    // ---- pass 1: online (max, sumexp) ----
    float M[4], S[4];
    #pragma unroll
    for (int j = 0; j < 4; ++j) { M[j] = -3.0e38f; S[j] = 0.f; }

    s16x8 c0h = *(const s16x8*)(khb + (size_t)(r) * NQ + kc);
    s16x8 c0l = *(const s16x8*)(klb + (size_t)(r) * NQ + kc);
    s16x8 c1h = *(const s16x8*)(khb + (size_t)(16 + r) * NQ + kc);
    s16x8 c1l = *(const s16x8*)(klb + (size_t)(16 + r) * NQ + kc);
    #pragma unroll 1
    for (int st = 0; st < 128; ++st) {
        s16x8 u0h = c0h, u0l = c0l, u1h = c1h, u1l = c1l;
        if (st < 127) {
            int m = (st + 1) * 32;
            c0h = *(const s16x8*)(khb + (size_t)(m + r) * NQ + kc);
            c0l = *(const s16x8*)(klb + (size_t)(m + r) * NQ + kc);
            c1h = *(const s16x8*)(khb + (size_t)(m + 16 + r) * NQ + kc);
            c1l = *(const s16x8*)(klb + (size_t)(m + 16 + r) * NQ + kc);
        }
        f32x4 e0 = {0.f, 0.f, 0.f, 0.f}, e1 = {0.f, 0.f, 0.f, 0.f};
        e0 = MFMA16(aqh, u0h, e0); e0 = MFMA16(aqh, u0l, e0); e0 = MFMA16(aql, u0h, e0);
        e1 = MFMA16(aqh, u1h, e1); e1 = MFMA16(aqh, u1l, e1); e1 = MFMA16(aql, u1h, e1);
        #pragma unroll
        for (int j = 0; j < 4; ++j) {
            float v0 = e0[j], v1 = e1[j];
            float nm = fmaxf(M[j], fmaxf(v0, v1));
            S[j] = S[j] * __expf(M[j] - nm) + __expf(v0 - nm) + __expf(v1 - nm);
            M[j] = nm;
        }
    }
    // combine the 16 m-columns (lanes sharing lane>>4 hold the same 4 rows)
    #pragma unroll
    for (int off = 1; off < 16; off <<= 1) {
        #pragma unroll
        for (int j = 0; j < 4; ++j) {
            float M2 = __shfl_xor(M[j], off), S2 = __shfl_xor(S[j], off);
            float nm = fmaxf(M[j], M2);
            S[j] = S[j] * __expf(M[j] - nm) + S2 * __expf(M2 - nm);
            M[j] = nm;
        }
    }
    float fI[4];
    #pragma unroll
    for (int j = 0; j < 4; ++j) fI[j] = 1.0f / S[j];

    __syncthreads();   // vs[0] staged

    // ---- pass 2: recompute + att write + PV ----
    f32x4 acc[16];
    #pragma unroll
    for (int ct = 0; ct < 16; ++ct) acc[ct] = (f32x4){0.f, 0.f, 0.f, 0.f};

    float* abase = att + ((size_t)b * NN + nw + r) * NN;  // frag row = lane&15

    c0h = *(const s16x8*)(khb + (size_t)(r) * NQ + kc);
    c0l = *(const s16x8*)(klb + (size_t)(r) * NQ + kc);
    c1h = *(const s16x8*)(khb + (size_t)(16 + r) * NQ + kc);
    c1l = *(const s16x8*)(klb + (size_t)(16 + r) * NQ + kc);
    int cur = 0;
    #pragma unroll 1
    for (int st = 0; st < 128; ++st) {
        const int m0 = st * 32;
        if (st < 127) {
            // stage next v tile into vs[cur^1]
            #pragma unroll
            for (int jj = 0; jj < 4; ++jj) {
                int s = jj * 256 + t, row = s >> 2, ch = s & 3;
                gload_lds16(vb + (size_t)row * NN + (m0 + 32) + ch * 8,
                            (char*)&vs[cur ^ 1][0] + (size_t)(jj * 256 + wv * 64) * 16);
            }
        }
        s16x8 u0h = c0h, u0l = c0l, u1h = c1h, u1l = c1l;
        if (st < 127) {
            int m = m0 + 32;
            c0h = *(const s16x8*)(khb + (size_t)(m + r) * NQ + kc);
            c0l = *(const s16x8*)(klb + (size_t)(m + r) * NQ + kc);
            c1h = *(const s16x8*)(khb + (size_t)(m + 16 + r) * NQ + kc);
            c1l = *(const s16x8*)(klb + (size_t)(m + 16 + r) * NQ + kc);
        }
        f32x4 e0 = {0.f, 0.f, 0.f, 0.f}, e1 = {0.f, 0.f, 0.f, 0.f};
        e0 = MFMA16(aqh, u0h, e0); e0 = MFMA16(aqh, u0l, e0); e0 = MFMA16(aql, u0h, e0);
        e1 = MFMA16(aqh, u1h, e1); e1 = MFMA16(aqh, u1l, e1); e1 = MFMA16(aql, u1h, e1);

        // normalized P -> bf16 -> per-wave LDS ([16 n][32 m])
        #pragma unroll
        for (int j = 0; j < 4; ++j) {
            float p0 = __expf(e0[j] - M[j]) * fI[j];
            float p1 = __expf(e1[j] - M[j]) * fI[j];
            int rw = hi * 4 + j;
            ps[wv][rw * 32 + r]      = __float2bfloat16(p0);
            ps[wv][rw * 32 + 16 + r] = __float2bfloat16(p1);
        }
        // read back as B-fragment (row = lane&15, k-offset = hi*8)
        s16x8 pf = *(const s16x8*)&ps[wv][r * 32 + kc];

        // att write: lane covers row (nw+r), cols m0+kc..+7 -> 2 NT float4 stores
        f32x4 w0, w1;
        w0[0] = bf2f(pf[0]); w0[1] = bf2f(pf[1]); w0[2] = bf2f(pf[2]); w0[3] = bf2f(pf[3]);
        w1[0] = bf2f(pf[4]); w1[1] = bf2f(pf[5]); w1[2] = bf2f(pf[6]); w1[3] = bf2f(pf[7]);
        __builtin_nontemporal_store(w0, (f32x4*)(abase + m0 + kc));
        __builtin_nontemporal_store(w1, (f32x4*)(abase + m0 + kc + 4));

        // PV: acc[c][n] += v[c][m] * P[n][m]
        #pragma unroll
        for (int ct = 0; ct < 16; ++ct) {
            s16x8 vf = *(const s16x8*)&vs[cur][(ct * 16 + r) * 32 + kc];
            acc[ct] = MFMA16(vf, pf, acc[ct]);
        }
        __syncthreads();
        cur ^= 1;
    }

    // epilogue: out[b][c][nw + r] = gamma*acc + x
    const float gm = gamma[0];
    #pragma unroll
    for (int ct = 0; ct < 16; ++ct) {
        #pragma unroll
        for (int j = 0; j < 4; ++j) {
            int c = ct * 16 + hi * 4 + j;
            size_t idx = ((size_t)b * NC + c) * NN + nw + r;
            out[idx] = gm * acc[ct][j] + x[idx];
        }
    }
}

extern "C" void kernel_launch(void* const* d_in, const int* in_sizes, int n_in,
                              void* d_out, int out_size, void* d_ws, size_t ws_size,
                              hipStream_t stream) {
    const float* x     = (const float*)d_in[0];
    const float* Wq    = (const float*)d_in[1];
    const float* bq    = (const float*)d_in[2];
    const float* Wk    = (const float*)d_in[3];
    const float* bk    = (const float*)d_in[4];
    const float* Wv    = (const float*)d_in[5];
    const float* bv    = (const float*)d_in[6];
    const float* gamma = (const float*)d_in[7];

    float* out = (float*)d_out;
    float* att = out + (size_t)NB * NC * NN;   // attention output region (268 MB)

    // workspace: qh | ql | kh | kl (each B*N*32 bf16 = 1 MB) | v bf16 (8 MB)
    const size_t qk_elems = (size_t)NB * NN * NQ;
    __hip_bfloat16* qh = (__hip_bfloat16*)d_ws;
    __hip_bfloat16* ql = qh + qk_elems;
    __hip_bfloat16* kh = ql + qk_elems;
    __hip_bfloat16* kl = kh + qk_elems;
    __hip_bfloat16* vo = kl + qk_elems;

    k_proj <<<dim3(NN / 64, NB), 512, 0, stream>>>(x, Wq, bq, Wk, bk, Wv, bv,
                                                   qh, ql, kh, kl, vo);
    k_fused<<<dim3(NN / 64, NB), 256, 0, stream>>>(qh, ql, kh, kl, vo,
                                                   x, gamma, out, att);
}

// Round 4
// 223.040 us; speedup vs baseline: 2.9434x; 1.2203x over previous
//
#include <hip/hip_runtime.h>
#include <hip/hip_bf16.h>

// Problem constants: B=4, C=256, H=W=64, N=4096, Cq=32
#define NB 4
#define NC 256
#define NQ 32
#define NN 4096

typedef __attribute__((ext_vector_type(4))) float f32x4;
typedef __attribute__((ext_vector_type(8))) short s16x8;

__device__ __forceinline__ float bf2f(short s) {
    return __uint_as_float(((unsigned int)(unsigned short)s) << 16);
}
#define MFMA16(a, b, c) __builtin_amdgcn_mfma_f32_16x16x32_bf16((a), (b), (c), 0, 0, 0)

// raw barrier: drain LDS ops only (NOT vmcnt — NT stores stay in flight)
__device__ __forceinline__ void block_sync_lds() {
    asm volatile("s_waitcnt lgkmcnt(0)" ::: "memory");
    __builtin_amdgcn_s_barrier();
}

// P-tile LDS swizzle (rows of 64 bf16 = 128B; XOR 16B-chunk by row&7)
__device__ __forceinline__ int pswz(int row, int col) {
    return row * 64 + (col ^ ((row & 7) << 3));
}

// ---------------- K1: fused QKV 1x1-conv projection (fp32 VALU) ----------------
// grid (N/64, B), block 512. LDS: x tile [256 c][64 n] fp32 = 64 KB.
// Loop-swapped: per 4-c chunk, 1 LDS b128 per c feeds all 10 o-accumulators.
__global__ __launch_bounds__(512, 2) void k_proj(
    const float* __restrict__ x,
    const float* __restrict__ Wq, const float* __restrict__ bq,
    const float* __restrict__ Wk, const float* __restrict__ bk,
    const float* __restrict__ Wv, const float* __restrict__ bv,
    __hip_bfloat16* __restrict__ qh, __hip_bfloat16* __restrict__ ql,
    __hip_bfloat16* __restrict__ kh, __hip_bfloat16* __restrict__ kl,
    __hip_bfloat16* __restrict__ vo)
{
    __shared__ __align__(16) float xs[NC * 64];
    const int b  = blockIdx.y;
    const int n0 = blockIdx.x * 64;
    const int t  = threadIdx.x;

    {
        const float* xb = x + (size_t)b * NC * NN + n0;
        #pragma unroll
        for (int it = 0; it < 8; ++it) {
            int i4 = t + it * 512;
            int c  = i4 >> 4;
            int nq = (i4 & 15) << 2;
            float4 v4 = *(const float4*)(xb + (size_t)c * NN + nq);
            *(float4*)&xs[c * 64 + nq] = v4;
        }
    }
    __syncthreads();

    const int g  = t >> 4;            // 0..31
    const int n4 = (t & 15) << 2;     // 0,4,...,60

    const float* Wr[10];
    float a[10][4];
    #pragma unroll
    for (int j = 0; j < 10; ++j) {
        int o = g + 32 * j;
        const float* Wrow; float bias;
        if (o < 32)      { Wrow = Wq + o * NC;        bias = bq[o]; }
        else if (o < 64) { Wrow = Wk + (o - 32) * NC; bias = bk[o - 32]; }
        else             { Wrow = Wv + (o - 64) * NC; bias = bv[o - 64]; }
        Wr[j] = Wrow;
        a[j][0] = a[j][1] = a[j][2] = a[j][3] = bias;
    }

    #pragma unroll 2
    for (int c0 = 0; c0 < NC; c0 += 4) {
        float4 xv[4];
        #pragma unroll
        for (int i = 0; i < 4; ++i) xv[i] = *(const float4*)&xs[(c0 + i) * 64 + n4];
        #pragma unroll
        for (int j = 0; j < 10; ++j) {
            float4 w = *(const float4*)(Wr[j] + c0);
            a[j][0] += w.x * xv[0].x + w.y * xv[1].x + w.z * xv[2].x + w.w * xv[3].x;
            a[j][1] += w.x * xv[0].y + w.y * xv[1].y + w.z * xv[2].y + w.w * xv[3].y;
            a[j][2] += w.x * xv[0].z + w.y * xv[1].z + w.z * xv[2].z + w.w * xv[3].z;
            a[j][3] += w.x * xv[0].w + w.y * xv[1].w + w.z * xv[2].w + w.w * xv[3].w;
        }
    }

    #pragma unroll
    for (int j = 0; j < 10; ++j) {
        int o = g + 32 * j;
        float a0 = fmaxf(a[j][0], 0.f), a1 = fmaxf(a[j][1], 0.f);
        float a2 = fmaxf(a[j][2], 0.f), a3 = fmaxf(a[j][3], 0.f);
        int nn = n0 + n4;
        if (o < 64) {
            __hip_bfloat16 *dh, *dl; int c;
            if (o < 32) { dh = qh; dl = ql; c = o; }
            else        { dh = kh; dl = kl; c = o - 32; }
            float vals[4] = {a0, a1, a2, a3};
            #pragma unroll
            for (int i = 0; i < 4; ++i) {
                float vv = vals[i];
                __hip_bfloat16 h = __float2bfloat16(vv);
                float lo = vv - __bfloat162float(h);
                size_t base = ((size_t)b * NN + nn + i) * NQ + c;
                dh[base] = h;
                dl[base] = __float2bfloat16(lo);
            }
        } else {
            union { __hip_bfloat16 h[4]; unsigned long long u; } pk;
            pk.h[0] = __float2bfloat16(a0); pk.h[1] = __float2bfloat16(a1);
            pk.h[2] = __float2bfloat16(a2); pk.h[3] = __float2bfloat16(a3);
            *(unsigned long long*)(vo + ((size_t)b * NC + (o - 64)) * NN + nn) = pk.u;
        }
    }
}

// ---------------- K2: fused attention, producer-consumer, 8 waves ----------------
// grid 256 blocks (XCD-swizzled), block 512 = 8 waves.
// Waves 0-3 (QK): own 16 n-rows each; pass-1 stats (m-half split w/ waves 4-7),
//   pass-2 produce bf16 P tiles (64n x 64m, double-buffered swizzled LDS) + att NT writes.
// Waves 4-7 (PV): own 64 c-rows each; consume P tiles, v straight from L2 to regs.
// One lgkmcnt-only barrier per 64-m step; NT stores never drained in-loop.
__global__ __launch_bounds__(512, 2) void k_fused(
    const __hip_bfloat16* __restrict__ qh, const __hip_bfloat16* __restrict__ ql,
    const __hip_bfloat16* __restrict__ kh, const __hip_bfloat16* __restrict__ kl,
    const __hip_bfloat16* __restrict__ v,
    const float* __restrict__ x, const float* __restrict__ gamma,
    float* __restrict__ out, float* __restrict__ att)
{
    __shared__ __align__(16) __hip_bfloat16 ps[2][64 * 64];  // 2 x 8 KB P tiles
    __shared__ float redM[8][16], redS[8][16];
    __shared__ float finM[64], finI[64];

    // XCD-aware bijective swizzle: each XCD gets 32 consecutive blocks = 1 batch slice
    const int flat = blockIdx.y * 64 + blockIdx.x;
    const int swzb = (flat & 7) * 32 + (flat >> 3);
    const int b  = swzb >> 6;
    const int n0 = (swzb & 63) * 64;

    const int t = threadIdx.x, wv = t >> 6, lane = t & 63;
    const int r = lane & 15, hi = lane >> 4, kc = hi * 8;
    const int wq = wv & 3;                 // n-tile index (both roles in pass 1)
    const int nw = n0 + wq * 16;

    const __hip_bfloat16* khb = kh + (size_t)b * NN * NQ;
    const __hip_bfloat16* klb = kl + (size_t)b * NN * NQ;
    const __hip_bfloat16* vb  = v  + (size_t)b * NC * NN;

    // q fragments for this wave's 16 rows
    s16x8 aqh = *(const s16x8*)(qh + ((size_t)b * NN + nw + r) * NQ + kc);
    s16x8 aql = *(const s16x8*)(ql + ((size_t)b * NN + nw + r) * NQ + kc);

    // ---- pass 1: online (max, sumexp); wave handles m-half (wv>>2) ----
    float M[4], S[4];
    #pragma unroll
    for (int j = 0; j < 4; ++j) { M[j] = -3.0e38f; S[j] = 0.f; }
    {
        const int hb = (wv >> 2) * (NN / 2);
        s16x8 c0h = *(const s16x8*)(khb + (size_t)(hb + r) * NQ + kc);
        s16x8 c0l = *(const s16x8*)(klb + (size_t)(hb + r) * NQ + kc);
        s16x8 c1h = *(const s16x8*)(khb + (size_t)(hb + 16 + r) * NQ + kc);
        s16x8 c1l = *(const s16x8*)(klb + (size_t)(hb + 16 + r) * NQ + kc);
        #pragma unroll 1
        for (int it = 0; it < 64; ++it) {
            s16x8 u0h = c0h, u0l = c0l, u1h = c1h, u1l = c1l;
            if (it < 63) {
                int m = hb + (it + 1) * 32;
                c0h = *(const s16x8*)(khb + (size_t)(m + r) * NQ + kc);
                c0l = *(const s16x8*)(klb + (size_t)(m + r) * NQ + kc);
                c1h = *(const s16x8*)(khb + (size_t)(m + 16 + r) * NQ + kc);
                c1l = *(const s16x8*)(klb + (size_t)(m + 16 + r) * NQ + kc);
            }
            f32x4 e0 = {0.f, 0.f, 0.f, 0.f}, e1 = {0.f, 0.f, 0.f, 0.f};
            e0 = MFMA16(aqh, u0h, e0); e0 = MFMA16(aqh, u0l, e0); e0 = MFMA16(aql, u0h, e0);
            e1 = MFMA16(aqh, u1h, e1); e1 = MFMA16(aqh, u1l, e1); e1 = MFMA16(aql, u1h, e1);
            #pragma unroll
            for (int j = 0; j < 4; ++j) {
                float v0 = e0[j], v1 = e1[j];
                float nm = fmaxf(M[j], fmaxf(v0, v1));
                S[j] = S[j] * __expf(M[j] - nm) + __expf(v0 - nm) + __expf(v1 - nm);
                M[j] = nm;
            }
        }
    }
    // combine across the 16 m-columns (lanes with same hi)
    #pragma unroll
    for (int off = 1; off < 16; off <<= 1) {
        #pragma unroll
        for (int j = 0; j < 4; ++j) {
            float M2 = __shfl_xor(M[j], off), S2 = __shfl_xor(S[j], off);
            float nm = fmaxf(M[j], M2);
            S[j] = S[j] * __expf(M[j] - nm) + S2 * __expf(M2 - nm);
            M[j] = nm;
        }
    }
    if (r == 0) {
        #pragma unroll
        for (int j = 0; j < 4; ++j) { redM[wv][hi * 4 + j] = M[j]; redS[wv][hi * 4 + j] = S[j]; }
    }
    __syncthreads();
    if (t < 64) {
        int tw = t >> 4, tl = t & 15;
        float M1 = redM[tw][tl], M2 = redM[tw + 4][tl];
        float Mf = fmaxf(M1, M2);
        float Sf = redS[tw][tl] * __expf(M1 - Mf) + redS[tw + 4][tl] * __expf(M2 - Mf);
        finM[t] = Mf; finI[t] = 1.0f / Sf;
    }
    __syncthreads();

    if (wv < 4) {
        // ================= QK producer =================
        float fM[4], fI[4];
        #pragma unroll
        for (int j = 0; j < 4; ++j) {
            fM[j] = finM[wq * 16 + hi * 4 + j];
            fI[j] = finI[wq * 16 + hi * 4 + j];
        }
        float* abase = att + ((size_t)b * NN + nw + r) * NN;
        const int rl = wq * 16 + r;          // readback row (local)

        s16x8 c0h = *(const s16x8*)(khb + (size_t)(r) * NQ + kc);
        s16x8 c0l = *(const s16x8*)(klb + (size_t)(r) * NQ + kc);
        s16x8 c1h = *(const s16x8*)(khb + (size_t)(16 + r) * NQ + kc);
        s16x8 c1l = *(const s16x8*)(klb + (size_t)(16 + r) * NQ + kc);

        #pragma unroll 1
        for (int st = 0; st < 64; ++st) {
            const int m0 = st * 64, buf = st & 1;
            #pragma unroll
            for (int ch = 0; ch < 2; ++ch) {
                s16x8 u0h = c0h, u0l = c0l, u1h = c1h, u1l = c1l;
                int mn = m0 + ch * 32 + 32;
                if (mn < NN) {
                    c0h = *(const s16x8*)(khb + (size_t)(mn + r) * NQ + kc);
                    c0l = *(const s16x8*)(klb + (size_t)(mn + r) * NQ + kc);
                    c1h = *(const s16x8*)(khb + (size_t)(mn + 16 + r) * NQ + kc);
                    c1l = *(const s16x8*)(klb + (size_t)(mn + 16 + r) * NQ + kc);
                }
                f32x4 e0 = {0.f, 0.f, 0.f, 0.f}, e1 = {0.f, 0.f, 0.f, 0.f};
                e0 = MFMA16(aqh, u0h, e0); e0 = MFMA16(aqh, u0l, e0); e0 = MFMA16(aql, u0h, e0);
                e1 = MFMA16(aqh, u1h, e1); e1 = MFMA16(aqh, u1l, e1); e1 = MFMA16(aql, u1h, e1);
                #pragma unroll
                for (int j = 0; j < 4; ++j) {
                    float p0 = __expf(e0[j] - fM[j]) * fI[j];
                    float p1 = __expf(e1[j] - fM[j]) * fI[j];
                    int row = wq * 16 + hi * 4 + j;
                    ps[buf][pswz(row, ch * 32 + r)]      = __float2bfloat16(p0);
                    ps[buf][pswz(row, ch * 32 + 16 + r)] = __float2bfloat16(p1);
                }
            }
            // att write: read back own rows' fragments, 2x16B NT per chunk
            #pragma unroll
            for (int ch = 0; ch < 2; ++ch) {
                s16x8 pf = *(const s16x8*)&ps[buf][pswz(rl, ch * 32 + kc)];
                f32x4 w0, w1;
                w0[0] = bf2f(pf[0]); w0[1] = bf2f(pf[1]); w0[2] = bf2f(pf[2]); w0[3] = bf2f(pf[3]);
                w1[0] = bf2f(pf[4]); w1[1] = bf2f(pf[5]); w1[2] = bf2f(pf[6]); w1[3] = bf2f(pf[7]);
                __builtin_nontemporal_store(w0, (f32x4*)(abase + m0 + ch * 32 + kc));
                __builtin_nontemporal_store(w1, (f32x4*)(abase + m0 + ch * 32 + kc + 4));
            }
            block_sync_lds();
        }
    } else {
        // ================= PV consumer =================
        const int cw = (wv - 4) * 64;
        f32x4 acc[4][4] = {};
        s16x8 vA[4], vB[4];
        #pragma unroll
        for (int ct = 0; ct < 4; ++ct)
            vA[ct] = *(const s16x8*)(vb + (size_t)(cw + ct * 16 + r) * NN + kc);

        #pragma unroll 1
        for (int st = 0; st < 64; ++st) {
            if (st > 0) {
                const int cst = st - 1, pb = cst & 1, mP = cst * 64;
                // k0 = 0 with vA; prefetch vB for k0 = 32
                #pragma unroll
                for (int ct = 0; ct < 4; ++ct)
                    vB[ct] = *(const s16x8*)(vb + (size_t)(cw + ct * 16 + r) * NN + mP + 32 + kc);
                s16x8 pf0[4];
                #pragma unroll
                for (int nt = 0; nt < 4; ++nt)
                    pf0[nt] = *(const s16x8*)&ps[pb][pswz(nt * 16 + r, kc)];
                __builtin_amdgcn_s_setprio(1);
                #pragma unroll
                for (int ct = 0; ct < 4; ++ct)
                    #pragma unroll
                    for (int nt = 0; nt < 4; ++nt)
                        acc[ct][nt] = MFMA16(vA[ct], pf0[nt], acc[ct][nt]);
                __builtin_amdgcn_s_setprio(0);
                // k0 = 32 with vB; prefetch vA for next step
                if (cst < 63) {
                    #pragma unroll
                    for (int ct = 0; ct < 4; ++ct)
                        vA[ct] = *(const s16x8*)(vb + (size_t)(cw + ct * 16 + r) * NN + mP + 64 + kc);
                }
                s16x8 pf1[4];
                #pragma unroll
                for (int nt = 0; nt < 4; ++nt)
                    pf1[nt] = *(const s16x8*)&ps[pb][pswz(nt * 16 + r, 32 + kc)];
                __builtin_amdgcn_s_setprio(1);
                #pragma unroll
                for (int ct = 0; ct < 4; ++ct)
                    #pragma unroll
                    for (int nt = 0; nt < 4; ++nt)
                        acc[ct][nt] = MFMA16(vB[ct], pf1[nt], acc[ct][nt]);
                __builtin_amdgcn_s_setprio(0);
            }
            block_sync_lds();
        }
        // tail: consume step 63 (ps[1], written before last barrier)
        {
            const int pb = 1, mP = 63 * 64;
            #pragma unroll
            for (int ct = 0; ct < 4; ++ct)
                vB[ct] = *(const s16x8*)(vb + (size_t)(cw + ct * 16 + r) * NN + mP + 32 + kc);
            s16x8 pf0[4], pf1[4];
            #pragma unroll
            for (int nt = 0; nt < 4; ++nt) {
                pf0[nt] = *(const s16x8*)&ps[pb][pswz(nt * 16 + r, kc)];
                pf1[nt] = *(const s16x8*)&ps[pb][pswz(nt * 16 + r, 32 + kc)];
            }
            #pragma unroll
            for (int ct = 0; ct < 4; ++ct)
                #pragma unroll
                for (int nt = 0; nt < 4; ++nt) {
                    acc[ct][nt] = MFMA16(vA[ct], pf0[nt], acc[ct][nt]);
                    acc[ct][nt] = MFMA16(vB[ct], pf1[nt], acc[ct][nt]);
                }
        }
        // epilogue: out = gamma*acc + x
        const float gm = gamma[0];
        #pragma unroll
        for (int ct = 0; ct < 4; ++ct) {
            #pragma unroll
            for (int nt = 0; nt < 4; ++nt) {
                #pragma unroll
                for (int j = 0; j < 4; ++j) {
                    int c = cw + ct * 16 + hi * 4 + j;
                    size_t idx = ((size_t)b * NC + c) * NN + n0 + nt * 16 + r;
                    out[idx] = gm * acc[ct][nt][j] + x[idx];
                }
            }
        }
    }
}

extern "C" void kernel_launch(void* const* d_in, const int* in_sizes, int n_in,
                              void* d_out, int out_size, void* d_ws, size_t ws_size,
                              hipStream_t stream) {
    const float* x     = (const float*)d_in[0];
    const float* Wq    = (const float*)d_in[1];
    const float* bq    = (const float*)d_in[2];
    const float* Wk    = (const float*)d_in[3];
    const float* bk    = (const float*)d_in[4];
    const float* Wv    = (const float*)d_in[5];
    const float* bv    = (const float*)d_in[6];
    const float* gamma = (const float*)d_in[7];

    float* out = (float*)d_out;
    float* att = out + (size_t)NB * NC * NN;   // attention output region (268 MB)

    // workspace: qh | ql | kh | kl (each B*N*32 bf16 = 1 MB) | v bf16 (8 MB)
    const size_t qk_elems = (size_t)NB * NN * NQ;
    __hip_bfloat16* qh = (__hip_bfloat16*)d_ws;
    __hip_bfloat16* ql = qh + qk_elems;
    __hip_bfloat16* kh = ql + qk_elems;
    __hip_bfloat16* kl = kh + qk_elems;
    __hip_bfloat16* vo = kl + qk_elems;

    k_proj <<<dim3(NN / 64, NB), 512, 0, stream>>>(x, Wq, bq, Wk, bk, Wv, bv,
                                                   qh, ql, kh, kl, vo);
    k_fused<<<dim3(NN / 64, NB), 512, 0, stream>>>(qh, ql, kh, kl, vo,
                                                   x, gamma, out, att);
}

// Round 6
// 202.349 us; speedup vs baseline: 3.2443x; 1.1023x over previous
//
#include <hip/hip_runtime.h>
#include <hip/hip_bf16.h>

// Problem constants: B=4, C=256, H=W=64, N=4096, Cq=32
#define NB 4
#define NC 256
#define NQ 32
#define NN 4096
#define LOG2E 1.4426950408889634f

typedef __attribute__((ext_vector_type(4))) float f32x4;
typedef __attribute__((ext_vector_type(8))) short s16x8;

#define MFMA16(a, b, c) __builtin_amdgcn_mfma_f32_16x16x32_bf16((a), (b), (c), 0, 0, 0)

// native 2^x (v_exp_f32); avoids math.h __exp2f macro clash
__device__ __forceinline__ float fexp2(float x) {
    float r;
    asm("v_exp_f32 %0, %1" : "=v"(r) : "v"(x));
    return r;
}

// raw barrier: drain LDS ops only (NOT vmcnt — NT stores stay in flight)
__device__ __forceinline__ void block_sync_lds() {
    asm volatile("s_waitcnt lgkmcnt(0)" ::: "memory");
    __builtin_amdgcn_s_barrier();
}

// P-tile LDS swizzle (rows of 64 bf16 = 128B; XOR 8-elem granule by row&7)
__device__ __forceinline__ int pswz(int row, int col) {
    return row * 64 + (col ^ ((row & 7) << 3));
}

// ---------------- K1: fused QKV 1x1-conv projection (fp32 VALU) ----------------
// grid (N/64, B), block 512. LDS: x tile [256 c][64 n] fp32 = 64 KB.
// q scaled by log2(e) (exp2-domain softmax); q,k as bf16 hi/lo in [n][32] layout;
// v bf16 [c][m].
__global__ __launch_bounds__(512, 2) void k_proj(
    const float* __restrict__ x,
    const float* __restrict__ Wq, const float* __restrict__ bq,
    const float* __restrict__ Wk, const float* __restrict__ bk,
    const float* __restrict__ Wv, const float* __restrict__ bv,
    __hip_bfloat16* __restrict__ qh, __hip_bfloat16* __restrict__ ql,
    __hip_bfloat16* __restrict__ kh, __hip_bfloat16* __restrict__ kl,
    __hip_bfloat16* __restrict__ vo)
{
    __shared__ __align__(16) float xs[NC * 64];
    const int b  = blockIdx.y;
    const int n0 = blockIdx.x * 64;
    const int t  = threadIdx.x;

    {
        const float* xb = x + (size_t)b * NC * NN + n0;
        #pragma unroll
        for (int it = 0; it < 8; ++it) {
            int i4 = t + it * 512;
            int c  = i4 >> 4;
            int nq = (i4 & 15) << 2;
            float4 v4 = *(const float4*)(xb + (size_t)c * NN + nq);
            *(float4*)&xs[c * 64 + nq] = v4;
        }
    }
    __syncthreads();

    const int g  = t >> 4;            // 0..31
    const int n4 = (t & 15) << 2;     // 0,4,...,60

    const float* Wr[10];
    float a[10][4];
    #pragma unroll
    for (int j = 0; j < 10; ++j) {
        int o = g + 32 * j;
        const float* Wrow; float bias;
        if (o < 32)      { Wrow = Wq + o * NC;        bias = bq[o]; }
        else if (o < 64) { Wrow = Wk + (o - 32) * NC; bias = bk[o - 32]; }
        else             { Wrow = Wv + (o - 64) * NC; bias = bv[o - 64]; }
        Wr[j] = Wrow;
        a[j][0] = a[j][1] = a[j][2] = a[j][3] = bias;
    }

    #pragma unroll 2
    for (int c0 = 0; c0 < NC; c0 += 4) {
        float4 xv[4];
        #pragma unroll
        for (int i = 0; i < 4; ++i) xv[i] = *(const float4*)&xs[(c0 + i) * 64 + n4];
        #pragma unroll
        for (int j = 0; j < 10; ++j) {
            float4 w = *(const float4*)(Wr[j] + c0);
            a[j][0] += w.x * xv[0].x + w.y * xv[1].x + w.z * xv[2].x + w.w * xv[3].x;
            a[j][1] += w.x * xv[0].y + w.y * xv[1].y + w.z * xv[2].y + w.w * xv[3].y;
            a[j][2] += w.x * xv[0].z + w.y * xv[1].z + w.z * xv[2].z + w.w * xv[3].z;
            a[j][3] += w.x * xv[0].w + w.y * xv[1].w + w.z * xv[2].w + w.w * xv[3].w;
        }
    }

    #pragma unroll
    for (int j = 0; j < 10; ++j) {
        int o = g + 32 * j;
        float a0 = fmaxf(a[j][0], 0.f), a1 = fmaxf(a[j][1], 0.f);
        float a2 = fmaxf(a[j][2], 0.f), a3 = fmaxf(a[j][3], 0.f);
        int nn = n0 + n4;
        if (o < 64) {
            __hip_bfloat16 *dh, *dl; int c; float sc;
            if (o < 32) { dh = qh; dl = ql; c = o;      sc = LOG2E; }  // exp2 domain
            else        { dh = kh; dl = kl; c = o - 32; sc = 1.0f;  }
            float vals[4] = {a0 * sc, a1 * sc, a2 * sc, a3 * sc};
            #pragma unroll
            for (int i = 0; i < 4; ++i) {
                float vv = vals[i];
                __hip_bfloat16 h = __float2bfloat16(vv);
                float lo = vv - __bfloat162float(h);
                size_t base = ((size_t)b * NN + nn + i) * NQ + c;
                dh[base] = h;
                dl[base] = __float2bfloat16(lo);
            }
        } else {
            union { __hip_bfloat16 h[4]; unsigned long long u; } pk;
            pk.h[0] = __float2bfloat16(a0); pk.h[1] = __float2bfloat16(a1);
            pk.h[2] = __float2bfloat16(a2); pk.h[3] = __float2bfloat16(a3);
            *(unsigned long long*)(vo + ((size_t)b * NC + (o - 64)) * NN + nn) = pk.u;
        }
    }
}

// ---------------- K2: fused attention, 16 waves (8 QK + 8 PV) ----------------
// grid 256 (XCD-chunked swizzle), block 1024. Block owns 64 n-rows.
// Operand-swapped QK: E[m][n], per-lane n = lane&15, m = (lane>>4)*4+j.
// Pass 1 (all 16 waves): wave = (n-tile w>>2, m-quarter w&3), online scalar (M,S).
// Pass 2: QK waves 0-7 (n-tile w>>1, m-half w&1): P = exp2(E - M)*I -> direct
//   fp32x4 NT att stores + 2x ds_write_b64 bf16 P into swizzled dbuf LDS.
// PV waves 8-15: 32 c-rows each; v frags from L2, P frags from LDS, 16 MFMA/step.
__global__ __launch_bounds__(1024, 4) void k_fused(
    const __hip_bfloat16* __restrict__ qh, const __hip_bfloat16* __restrict__ ql,
    const __hip_bfloat16* __restrict__ kh, const __hip_bfloat16* __restrict__ kl,
    const __hip_bfloat16* __restrict__ v,
    const float* __restrict__ x, const float* __restrict__ gamma,
    float* __restrict__ out, float* __restrict__ att)
{
    __shared__ __align__(16) __hip_bfloat16 ps[2][64 * 64];  // 2 x 8 KB P tiles
    __shared__ float redM[16][16], redS[16][16];
    __shared__ float finM[64], finI[64];

    // XCD chunked swizzle: 32 consecutive flat blocks per XCD (half a batch)
    const int bid  = blockIdx.x;
    const int flat = (bid & 7) * 32 + (bid >> 3);
    const int b    = flat >> 6;
    const int n0   = (flat & 63) * 64;

    const int t = threadIdx.x, wv = t >> 6, lane = t & 63;
    const int r = lane & 15, hi = lane >> 4, kc = hi * 8;

    const __hip_bfloat16* khb = kh + (size_t)b * NN * NQ;
    const __hip_bfloat16* klb = kl + (size_t)b * NN * NQ;
    const __hip_bfloat16* vb  = v  + (size_t)b * NC * NN;

    // ---- pass 1: online (max, sumexp), all 16 waves ----
    {
        const int nt1 = wv >> 2, mq = wv & 3;
        const int nw = n0 + nt1 * 16;
        const s16x8 aqh = *(const s16x8*)(qh + ((size_t)b * NN + nw + r) * NQ + kc);
        const s16x8 aql = *(const s16x8*)(ql + ((size_t)b * NN + nw + r) * NQ + kc);
        const int mb = mq * 1024;
        float M = -3.0e38f, S = 0.f;
        s16x8 c0h = *(const s16x8*)(khb + (size_t)(mb + r) * NQ + kc);
        s16x8 c0l = *(const s16x8*)(klb + (size_t)(mb + r) * NQ + kc);
        s16x8 c1h = *(const s16x8*)(khb + (size_t)(mb + 16 + r) * NQ + kc);
        s16x8 c1l = *(const s16x8*)(klb + (size_t)(mb + 16 + r) * NQ + kc);
        #pragma unroll 1
        for (int it = 0; it < 32; ++it) {
            s16x8 u0h = c0h, u0l = c0l, u1h = c1h, u1l = c1l;
            if (it < 31) {
                int m = mb + (it + 1) * 32;
                c0h = *(const s16x8*)(khb + (size_t)(m + r) * NQ + kc);
                c0l = *(const s16x8*)(klb + (size_t)(m + r) * NQ + kc);
                c1h = *(const s16x8*)(khb + (size_t)(m + 16 + r) * NQ + kc);
                c1l = *(const s16x8*)(klb + (size_t)(m + 16 + r) * NQ + kc);
            }
            f32x4 e0 = {0.f, 0.f, 0.f, 0.f}, e1 = {0.f, 0.f, 0.f, 0.f};
            e0 = MFMA16(u0h, aqh, e0); e0 = MFMA16(u0l, aqh, e0); e0 = MFMA16(u0h, aql, e0);
            e1 = MFMA16(u1h, aqh, e1); e1 = MFMA16(u1l, aqh, e1); e1 = MFMA16(u1h, aql, e1);
            float mx = fmaxf(fmaxf(fmaxf(e0[0], e0[1]), fmaxf(e0[2], e0[3])),
                             fmaxf(fmaxf(e1[0], e1[1]), fmaxf(e1[2], e1[3])));
            float nm = fmaxf(M, mx);
            float s8 = fexp2(e0[0] - nm) + fexp2(e0[1] - nm) +
                       fexp2(e0[2] - nm) + fexp2(e0[3] - nm) +
                       fexp2(e1[0] - nm) + fexp2(e1[1] - nm) +
                       fexp2(e1[2] - nm) + fexp2(e1[3] - nm);
            S = S * fexp2(M - nm) + s8;
            M = nm;
        }
        // combine lanes {r, r+16, r+32, r+48} (same n)
        #pragma unroll
        for (int off = 16; off <= 32; off <<= 1) {
            float M2 = __shfl_xor(M, off), S2 = __shfl_xor(S, off);
            float nm = fmaxf(M, M2);
            S = S * fexp2(M - nm) + S2 * fexp2(M2 - nm);
            M = nm;
        }
        if (lane < 16) { redM[wv][r] = M; redS[wv][r] = S; }
    }
    __syncthreads();
    if (t < 64) {
        const int w0 = (t >> 4) * 4, tl = t & 15;
        float M = redM[w0][tl], S = redS[w0][tl];
        #pragma unroll
        for (int i = 1; i < 4; ++i) {
            float M2 = redM[w0 + i][tl], S2 = redS[w0 + i][tl];
            float nm = fmaxf(M, M2);
            S = S * fexp2(M - nm) + S2 * fexp2(M2 - nm);
            M = nm;
        }
        finM[t] = M; finI[t] = 1.0f / S;
    }
    __syncthreads();

    if (wv < 8) {
        // ================= QK producer =================
        const int nt = wv >> 1, mh = wv & 1;
        const int nw = n0 + nt * 16;
        const s16x8 aqh = *(const s16x8*)(qh + ((size_t)b * NN + nw + r) * NQ + kc);
        const s16x8 aql = *(const s16x8*)(ql + ((size_t)b * NN + nw + r) * NQ + kc);
        const float fM = finM[nt * 16 + r], fI = finI[nt * 16 + r];
        float* arow = att + ((size_t)b * NN + nw + r) * NN;   // this lane's att row
        const int prow = nt * 16 + r;                          // P LDS row
        const int pc0  = mh * 32 + hi * 4;                     // P LDS col base

        int mt = mh * 32;
        s16x8 c0h = *(const s16x8*)(khb + (size_t)(mt + r) * NQ + kc);
        s16x8 c0l = *(const s16x8*)(klb + (size_t)(mt + r) * NQ + kc);
        s16x8 c1h = *(const s16x8*)(khb + (size_t)(mt + 16 + r) * NQ + kc);
        s16x8 c1l = *(const s16x8*)(klb + (size_t)(mt + 16 + r) * NQ + kc);

        #pragma unroll 1
        for (int st = 0; st < 64; ++st) {
            const int buf = st & 1;
            s16x8 u0h = c0h, u0l = c0l, u1h = c1h, u1l = c1l;
            if (st < 63) {
                int mn = mt + 64;
                c0h = *(const s16x8*)(khb + (size_t)(mn + r) * NQ + kc);
                c0l = *(const s16x8*)(klb + (size_t)(mn + r) * NQ + kc);
                c1h = *(const s16x8*)(khb + (size_t)(mn + 16 + r) * NQ + kc);
                c1l = *(const s16x8*)(klb + (size_t)(mn + 16 + r) * NQ + kc);
            }
            f32x4 e0 = {0.f, 0.f, 0.f, 0.f}, e1 = {0.f, 0.f, 0.f, 0.f};
            e0 = MFMA16(u0h, aqh, e0); e0 = MFMA16(u0l, aqh, e0); e0 = MFMA16(u0h, aql, e0);
            e1 = MFMA16(u1h, aqh, e1); e1 = MFMA16(u1l, aqh, e1); e1 = MFMA16(u1h, aql, e1);

            f32x4 w0, w1;
            #pragma unroll
            for (int j = 0; j < 4; ++j) {
                w0[j] = fexp2(e0[j] - fM) * fI;
                w1[j] = fexp2(e1[j] - fM) * fI;
            }
            // att: fp32 direct from registers, 2x16B NT (m = mt+hi*4.. / +16)
            __builtin_nontemporal_store(w0, (f32x4*)(arow + mt + hi * 4));
            __builtin_nontemporal_store(w1, (f32x4*)(arow + mt + 16 + hi * 4));
            // P tile: 2x ds_write_b64 (4 consecutive m each), swizzled
            union { __hip_bfloat16 h[4]; unsigned long long u; } pk0, pk1;
            #pragma unroll
            for (int j = 0; j < 4; ++j) {
                pk0.h[j] = __float2bfloat16(w0[j]);
                pk1.h[j] = __float2bfloat16(w1[j]);
            }
            *(unsigned long long*)&ps[buf][pswz(prow, pc0)]      = pk0.u;
            *(unsigned long long*)&ps[buf][pswz(prow, pc0 + 16)] = pk1.u;

            block_sync_lds();
            mt += 64;
        }
    } else {
        // ================= PV consumer =================
        const int cw = (wv - 8) * 32;
        f32x4 acc[2][4] = {};

        #pragma unroll 1
        for (int st = 0; st < 64; ++st) {
            if (st > 0) {
                const int cst = st - 1, pb = cst & 1, mP = cst * 64;
                s16x8 vf0[2], vf1[2], pf0[4], pf1[4];
                #pragma unroll
                for (int ct = 0; ct < 2; ++ct)
                    vf0[ct] = *(const s16x8*)(vb + (size_t)(cw + ct * 16 + r) * NN + mP + kc);
                #pragma unroll
                for (int nt = 0; nt < 4; ++nt)
                    pf0[nt] = *(const s16x8*)&ps[pb][pswz(nt * 16 + r, kc)];
                #pragma unroll
                for (int ct = 0; ct < 2; ++ct)
                    vf1[ct] = *(const s16x8*)(vb + (size_t)(cw + ct * 16 + r) * NN + mP + 32 + kc);
                #pragma unroll
                for (int nt = 0; nt < 4; ++nt)
                    pf1[nt] = *(const s16x8*)&ps[pb][pswz(nt * 16 + r, 32 + kc)];
                __builtin_amdgcn_s_setprio(1);
                #pragma unroll
                for (int ct = 0; ct < 2; ++ct)
                    #pragma unroll
                    for (int nt = 0; nt < 4; ++nt)
                        acc[ct][nt] = MFMA16(vf0[ct], pf0[nt], acc[ct][nt]);
                #pragma unroll
                for (int ct = 0; ct < 2; ++ct)
                    #pragma unroll
                    for (int nt = 0; nt < 4; ++nt)
                        acc[ct][nt] = MFMA16(vf1[ct], pf1[nt], acc[ct][nt]);
                __builtin_amdgcn_s_setprio(0);
            }
            block_sync_lds();
        }
        // tail: consume step 63 (ps[1])
        {
            const int mP = 63 * 64;
            s16x8 vf0[2], vf1[2], pf0[4], pf1[4];
            #pragma unroll
            for (int ct = 0; ct < 2; ++ct) {
                vf0[ct] = *(const s16x8*)(vb + (size_t)(cw + ct * 16 + r) * NN + mP + kc);
                vf1[ct] = *(const s16x8*)(vb + (size_t)(cw + ct * 16 + r) * NN + mP + 32 + kc);
            }
            #pragma unroll
            for (int nt = 0; nt < 4; ++nt) {
                pf0[nt] = *(const s16x8*)&ps[1][pswz(nt * 16 + r, kc)];
                pf1[nt] = *(const s16x8*)&ps[1][pswz(nt * 16 + r, 32 + kc)];
            }
            #pragma unroll
            for (int ct = 0; ct < 2; ++ct)
                #pragma unroll
                for (int nt = 0; nt < 4; ++nt) {
                    acc[ct][nt] = MFMA16(vf0[ct], pf0[nt], acc[ct][nt]);
                    acc[ct][nt] = MFMA16(vf1[ct], pf1[nt], acc[ct][nt]);
                }
        }
        // epilogue: out = gamma*acc + x
        const float gm = gamma[0];
        #pragma unroll
        for (int ct = 0; ct < 2; ++ct) {
            #pragma unroll
            for (int nt = 0; nt < 4; ++nt) {
                #pragma unroll
                for (int j = 0; j < 4; ++j) {
                    int c = cw + ct * 16 + hi * 4 + j;
                    size_t idx = ((size_t)b * NC + c) * NN + n0 + nt * 16 + r;
                    out[idx] = gm * acc[ct][nt][j] + x[idx];
                }
            }
        }
    }
}

extern "C" void kernel_launch(void* const* d_in, const int* in_sizes, int n_in,
                              void* d_out, int out_size, void* d_ws, size_t ws_size,
                              hipStream_t stream) {
    const float* x     = (const float*)d_in[0];
    const float* Wq    = (const float*)d_in[1];
    const float* bq    = (const float*)d_in[2];
    const float* Wk    = (const float*)d_in[3];
    const float* bk    = (const float*)d_in[4];
    const float* Wv    = (const float*)d_in[5];
    const float* bv    = (const float*)d_in[6];
    const float* gamma = (const float*)d_in[7];

    float* out = (float*)d_out;
    float* att = out + (size_t)NB * NC * NN;   // attention output region (268 MB)

    // workspace: qh | ql | kh | kl (each B*N*32 bf16 = 1 MB) | v bf16 (8 MB)
    const size_t qk_elems = (size_t)NB * NN * NQ;
    __hip_bfloat16* qh = (__hip_bfloat16*)d_ws;
    __hip_bfloat16* ql = qh + qk_elems;
    __hip_bfloat16* kh = ql + qk_elems;
    __hip_bfloat16* kl = kh + qk_elems;
    __hip_bfloat16* vo = kl + qk_elems;

    k_proj <<<dim3(NN / 64, NB), 512, 0, stream>>>(x, Wq, bq, Wk, bk, Wv, bv,
                                                   qh, ql, kh, kl, vo);
    k_fused<<<dim3(256), 1024, 0, stream>>>(qh, ql, kh, kl, vo,
                                            x, gamma, out, att);
}

// Round 7
// 200.821 us; speedup vs baseline: 3.2690x; 1.0076x over previous
//
#include <hip/hip_runtime.h>
#include <hip/hip_bf16.h>

// Problem constants: B=4, C=256, H=W=64, N=4096, Cq=32
#define NB 4
#define NC 256
#define NQ 32
#define NN 4096
#define LOG2E 1.4426950408889634f

typedef __attribute__((ext_vector_type(4))) float f32x4;
typedef __attribute__((ext_vector_type(8))) short s16x8;

#define MFMA16(a, b, c) __builtin_amdgcn_mfma_f32_16x16x32_bf16((a), (b), (c), 0, 0, 0)

// native 2^x (v_exp_f32); avoids math.h __exp2f macro clash
__device__ __forceinline__ float fexp2(float x) {
    float r;
    asm("v_exp_f32 %0, %1" : "=v"(r) : "v"(x));
    return r;
}
__device__ __forceinline__ float bf2f(short s) {
    return __uint_as_float(((unsigned int)(unsigned short)s) << 16);
}

// raw barrier: drain LDS ops only (NOT vmcnt — NT stores stay in flight)
__device__ __forceinline__ void block_sync_lds() {
    asm volatile("s_waitcnt lgkmcnt(0)" ::: "memory");
    __builtin_amdgcn_s_barrier();
}

// P-tile LDS swizzle (rows of 64 bf16 = 128B; XOR 8-elem granule by row&7)
__device__ __forceinline__ int pswz(int row, int col) {
    return row * 64 + (col ^ ((row & 7) << 3));
}

// ---------------- K1: fused QKV 1x1-conv projection (fp32 VALU) ----------------
__global__ __launch_bounds__(512, 2) void k_proj(
    const float* __restrict__ x,
    const float* __restrict__ Wq, const float* __restrict__ bq,
    const float* __restrict__ Wk, const float* __restrict__ bk,
    const float* __restrict__ Wv, const float* __restrict__ bv,
    __hip_bfloat16* __restrict__ qh, __hip_bfloat16* __restrict__ ql,
    __hip_bfloat16* __restrict__ kh, __hip_bfloat16* __restrict__ kl,
    __hip_bfloat16* __restrict__ vo)
{
    __shared__ __align__(16) float xs[NC * 64];
    const int b  = blockIdx.y;
    const int n0 = blockIdx.x * 64;
    const int t  = threadIdx.x;

    {
        const float* xb = x + (size_t)b * NC * NN + n0;
        #pragma unroll
        for (int it = 0; it < 8; ++it) {
            int i4 = t + it * 512;
            int c  = i4 >> 4;
            int nq = (i4 & 15) << 2;
            float4 v4 = *(const float4*)(xb + (size_t)c * NN + nq);
            *(float4*)&xs[c * 64 + nq] = v4;
        }
    }
    __syncthreads();

    const int g  = t >> 4;            // 0..31
    const int n4 = (t & 15) << 2;     // 0,4,...,60

    const float* Wr[10];
    float a[10][4];
    #pragma unroll
    for (int j = 0; j < 10; ++j) {
        int o = g + 32 * j;
        const float* Wrow; float bias;
        if (o < 32)      { Wrow = Wq + o * NC;        bias = bq[o]; }
        else if (o < 64) { Wrow = Wk + (o - 32) * NC; bias = bk[o - 32]; }
        else             { Wrow = Wv + (o - 64) * NC; bias = bv[o - 64]; }
        Wr[j] = Wrow;
        a[j][0] = a[j][1] = a[j][2] = a[j][3] = bias;
    }

    #pragma unroll 2
    for (int c0 = 0; c0 < NC; c0 += 4) {
        float4 xv[4];
        #pragma unroll
        for (int i = 0; i < 4; ++i) xv[i] = *(const float4*)&xs[(c0 + i) * 64 + n4];
        #pragma unroll
        for (int j = 0; j < 10; ++j) {
            float4 w = *(const float4*)(Wr[j] + c0);
            a[j][0] += w.x * xv[0].x + w.y * xv[1].x + w.z * xv[2].x + w.w * xv[3].x;
            a[j][1] += w.x * xv[0].y + w.y * xv[1].y + w.z * xv[2].y + w.w * xv[3].y;
            a[j][2] += w.x * xv[0].z + w.y * xv[1].z + w.z * xv[2].z + w.w * xv[3].z;
            a[j][3] += w.x * xv[0].w + w.y * xv[1].w + w.z * xv[2].w + w.w * xv[3].w;
        }
    }

    #pragma unroll
    for (int j = 0; j < 10; ++j) {
        int o = g + 32 * j;
        float a0 = fmaxf(a[j][0], 0.f), a1 = fmaxf(a[j][1], 0.f);
        float a2 = fmaxf(a[j][2], 0.f), a3 = fmaxf(a[j][3], 0.f);
        int nn = n0 + n4;
        if (o < 64) {
            __hip_bfloat16 *dh, *dl; int c; float sc;
            if (o < 32) { dh = qh; dl = ql; c = o;      sc = LOG2E; }  // exp2 domain
            else        { dh = kh; dl = kl; c = o - 32; sc = 1.0f;  }
            float vals[4] = {a0 * sc, a1 * sc, a2 * sc, a3 * sc};
            #pragma unroll
            for (int i = 0; i < 4; ++i) {
                float vv = vals[i];
                __hip_bfloat16 h = __float2bfloat16(vv);
                float lo = vv - __bfloat162float(h);
                size_t base = ((size_t)b * NN + nn + i) * NQ + c;
                dh[base] = h;
                dl[base] = __float2bfloat16(lo);
            }
        } else {
            union { __hip_bfloat16 h[4]; unsigned long long u; } pk;
            pk.h[0] = __float2bfloat16(a0); pk.h[1] = __float2bfloat16(a1);
            pk.h[2] = __float2bfloat16(a2); pk.h[3] = __float2bfloat16(a3);
            *(unsigned long long*)(vo + ((size_t)b * NC + (o - 64)) * NN + nn) = pk.u;
        }
    }
}

// ---------------- K2: fused attention, 16 waves (8 QK + 8 PV) ----------------
// QK waves (0-7): clean vmcnt (k loads only) — MFMA energy, softmax, ds_write P.
// PV waves (8-15): own 32 c-rows; v loads pipelined 1 step ahead of the NT att
// stores they now issue themselves (expanded from the P fragments they already
// read for MFMA). att values are bf16-rounded (same as R3; abs err ~0.002).
__global__ __launch_bounds__(1024, 4) void k_fused(
    const __hip_bfloat16* __restrict__ qh, const __hip_bfloat16* __restrict__ ql,
    const __hip_bfloat16* __restrict__ kh, const __hip_bfloat16* __restrict__ kl,
    const __hip_bfloat16* __restrict__ v,
    const float* __restrict__ x, const float* __restrict__ gamma,
    float* __restrict__ out, float* __restrict__ att)
{
    __shared__ __align__(16) __hip_bfloat16 ps[2][64 * 64];  // 2 x 8 KB P tiles
    __shared__ float redM[16][16], redS[16][16];
    __shared__ float finM[64], finI[64];

    // XCD chunked swizzle: 32 consecutive flat blocks per XCD (half a batch)
    const int bid  = blockIdx.x;
    const int flat = (bid & 7) * 32 + (bid >> 3);
    const int b    = flat >> 6;
    const int n0   = (flat & 63) * 64;

    const int t = threadIdx.x, wv = t >> 6, lane = t & 63;
    const int r = lane & 15, hi = lane >> 4, kc = hi * 8;

    const __hip_bfloat16* khb = kh + (size_t)b * NN * NQ;
    const __hip_bfloat16* klb = kl + (size_t)b * NN * NQ;
    const __hip_bfloat16* vb  = v  + (size_t)b * NC * NN;

    // ---- pass 1: online (max, sumexp), all 16 waves ----
    {
        const int nt1 = wv >> 2, mq = wv & 3;
        const int nw = n0 + nt1 * 16;
        const s16x8 aqh = *(const s16x8*)(qh + ((size_t)b * NN + nw + r) * NQ + kc);
        const s16x8 aql = *(const s16x8*)(ql + ((size_t)b * NN + nw + r) * NQ + kc);
        const int mb = mq * 1024;
        float M = -3.0e38f, S = 0.f;
        s16x8 c0h = *(const s16x8*)(khb + (size_t)(mb + r) * NQ + kc);
        s16x8 c0l = *(const s16x8*)(klb + (size_t)(mb + r) * NQ + kc);
        s16x8 c1h = *(const s16x8*)(khb + (size_t)(mb + 16 + r) * NQ + kc);
        s16x8 c1l = *(const s16x8*)(klb + (size_t)(mb + 16 + r) * NQ + kc);
        #pragma unroll 1
        for (int it = 0; it < 32; ++it) {
            s16x8 u0h = c0h, u0l = c0l, u1h = c1h, u1l = c1l;
            if (it < 31) {
                int m = mb + (it + 1) * 32;
                c0h = *(const s16x8*)(khb + (size_t)(m + r) * NQ + kc);
                c0l = *(const s16x8*)(klb + (size_t)(m + r) * NQ + kc);
                c1h = *(const s16x8*)(khb + (size_t)(m + 16 + r) * NQ + kc);
                c1l = *(const s16x8*)(klb + (size_t)(m + 16 + r) * NQ + kc);
            }
            f32x4 e0 = {0.f, 0.f, 0.f, 0.f}, e1 = {0.f, 0.f, 0.f, 0.f};
            e0 = MFMA16(u0h, aqh, e0); e0 = MFMA16(u0l, aqh, e0); e0 = MFMA16(u0h, aql, e0);
            e1 = MFMA16(u1h, aqh, e1); e1 = MFMA16(u1l, aqh, e1); e1 = MFMA16(u1h, aql, e1);
            float mx = fmaxf(fmaxf(fmaxf(e0[0], e0[1]), fmaxf(e0[2], e0[3])),
                             fmaxf(fmaxf(e1[0], e1[1]), fmaxf(e1[2], e1[3])));
            float nm = fmaxf(M, mx);
            float s8 = fexp2(e0[0] - nm) + fexp2(e0[1] - nm) +
                       fexp2(e0[2] - nm) + fexp2(e0[3] - nm) +
                       fexp2(e1[0] - nm) + fexp2(e1[1] - nm) +
                       fexp2(e1[2] - nm) + fexp2(e1[3] - nm);
            S = S * fexp2(M - nm) + s8;
            M = nm;
        }
        #pragma unroll
        for (int off = 16; off <= 32; off <<= 1) {
            float M2 = __shfl_xor(M, off), S2 = __shfl_xor(S, off);
            float nm = fmaxf(M, M2);
            S = S * fexp2(M - nm) + S2 * fexp2(M2 - nm);
            M = nm;
        }
        if (lane < 16) { redM[wv][r] = M; redS[wv][r] = S; }
    }
    __syncthreads();
    if (t < 64) {
        const int w0 = (t >> 4) * 4, tl = t & 15;
        float M = redM[w0][tl], S = redS[w0][tl];
        #pragma unroll
        for (int i = 1; i < 4; ++i) {
            float M2 = redM[w0 + i][tl], S2 = redS[w0 + i][tl];
            float nm = fmaxf(M, M2);
            S = S * fexp2(M - nm) + S2 * fexp2(M2 - nm);
            M = nm;
        }
        finM[t] = M; finI[t] = 1.0f / S;
    }
    __syncthreads();

    if (wv < 8) {
        // ================= QK producer (store-free, clean vmcnt) =================
        const int nt = wv >> 1, mh = wv & 1;
        const int nw = n0 + nt * 16;
        const s16x8 aqh = *(const s16x8*)(qh + ((size_t)b * NN + nw + r) * NQ + kc);
        const s16x8 aql = *(const s16x8*)(ql + ((size_t)b * NN + nw + r) * NQ + kc);
        const float fM = finM[nt * 16 + r], fI = finI[nt * 16 + r];
        const int prow = nt * 16 + r;          // P LDS row
        const int pc0  = mh * 32 + hi * 4;     // P LDS col base

        int mt = mh * 32;
        s16x8 c0h = *(const s16x8*)(khb + (size_t)(mt + r) * NQ + kc);
        s16x8 c0l = *(const s16x8*)(klb + (size_t)(mt + r) * NQ + kc);
        s16x8 c1h = *(const s16x8*)(khb + (size_t)(mt + 16 + r) * NQ + kc);
        s16x8 c1l = *(const s16x8*)(klb + (size_t)(mt + 16 + r) * NQ + kc);

        #pragma unroll 1
        for (int st = 0; st < 64; ++st) {
            const int buf = st & 1;
            s16x8 u0h = c0h, u0l = c0l, u1h = c1h, u1l = c1l;
            if (st < 63) {
                int mn = mt + 64;
                c0h = *(const s16x8*)(khb + (size_t)(mn + r) * NQ + kc);
                c0l = *(const s16x8*)(klb + (size_t)(mn + r) * NQ + kc);
                c1h = *(const s16x8*)(khb + (size_t)(mn + 16 + r) * NQ + kc);
                c1l = *(const s16x8*)(klb + (size_t)(mn + 16 + r) * NQ + kc);
            }
            f32x4 e0 = {0.f, 0.f, 0.f, 0.f}, e1 = {0.f, 0.f, 0.f, 0.f};
            e0 = MFMA16(u0h, aqh, e0); e0 = MFMA16(u0l, aqh, e0); e0 = MFMA16(u0h, aql, e0);
            e1 = MFMA16(u1h, aqh, e1); e1 = MFMA16(u1l, aqh, e1); e1 = MFMA16(u1h, aql, e1);

            union { __hip_bfloat16 h[4]; unsigned long long u; } pk0, pk1;
            #pragma unroll
            for (int j = 0; j < 4; ++j) {
                pk0.h[j] = __float2bfloat16(fexp2(e0[j] - fM) * fI);
                pk1.h[j] = __float2bfloat16(fexp2(e1[j] - fM) * fI);
            }
            *(unsigned long long*)&ps[buf][pswz(prow, pc0)]      = pk0.u;
            *(unsigned long long*)&ps[buf][pswz(prow, pc0 + 16)] = pk1.u;

            block_sync_lds();
            mt += 64;
        }
    } else {
        // ================= PV consumer + att writer =================
        const int pw  = wv - 8, cw = pw * 32;
        const int ntw = pw >> 1;                       // n-tile this wave writes
        const bool wact = ((r >> 3) == (pw & 1));      // lanes holding those rows
        float* arow = att + ((size_t)b * NN + n0 + pw * 8 + (r & 7)) * NN;
        f32x4 acc[2][4] = {};

        // prologue: v loads for step 0
        s16x8 vA00 = *(const s16x8*)(vb + (size_t)(cw + r) * NN + kc);
        s16x8 vA01 = *(const s16x8*)(vb + (size_t)(cw + 16 + r) * NN + kc);
        s16x8 vA10 = *(const s16x8*)(vb + (size_t)(cw + r) * NN + 32 + kc);
        s16x8 vA11 = *(const s16x8*)(vb + (size_t)(cw + 16 + r) * NN + 32 + kc);

        block_sync_lds();   // iteration st=0 (QK fills ps[0])

        #pragma unroll 1
        for (int st = 1; st < 64; ++st) {
            const int pb = (st - 1) & 1;
            const int mP = (st - 1) * 64;
            s16x8 pf[4];
            // chunk 0 (m = mP..mP+31)
            #pragma unroll
            for (int nt = 0; nt < 4; ++nt)
                pf[nt] = *(const s16x8*)&ps[pb][pswz(nt * 16 + r, kc)];
            __builtin_amdgcn_s_setprio(1);
            #pragma unroll
            for (int nt = 0; nt < 4; ++nt) {
                acc[0][nt] = MFMA16(vA00, pf[nt], acc[0][nt]);
                acc[1][nt] = MFMA16(vA01, pf[nt], acc[1][nt]);
            }
            __builtin_amdgcn_s_setprio(0);
            // chunk 1 (m = mP+32..mP+63)
            #pragma unroll
            for (int nt = 0; nt < 4; ++nt)
                pf[nt] = *(const s16x8*)&ps[pb][pswz(nt * 16 + r, 32 + kc)];
            __builtin_amdgcn_s_setprio(1);
            #pragma unroll
            for (int nt = 0; nt < 4; ++nt) {
                acc[0][nt] = MFMA16(vA10, pf[nt], acc[0][nt]);
                acc[1][nt] = MFMA16(vA11, pf[nt], acc[1][nt]);
            }
            __builtin_amdgcn_s_setprio(0);

            // issue NEXT step's v loads BEFORE this step's stores (vmcnt slack)
            {
                const int mN = st * 64;
                vA00 = *(const s16x8*)(vb + (size_t)(cw + r) * NN + mN + kc);
                vA01 = *(const s16x8*)(vb + (size_t)(cw + 16 + r) * NN + mN + kc);
                vA10 = *(const s16x8*)(vb + (size_t)(cw + r) * NN + mN + 32 + kc);
                vA11 = *(const s16x8*)(vb + (size_t)(cw + 16 + r) * NN + mN + 32 + kc);
            }
            // att NT stores for step st-1 (from re-read P frags, bf16-rounded)
            if (wact) {
                s16x8 q0 = *(const s16x8*)&ps[pb][pswz(ntw * 16 + r, kc)];
                s16x8 q1 = *(const s16x8*)&ps[pb][pswz(ntw * 16 + r, 32 + kc)];
                f32x4 w0, w1, w2, w3;
                #pragma unroll
                for (int j = 0; j < 4; ++j) {
                    w0[j] = bf2f(q0[j]); w1[j] = bf2f(q0[j + 4]);
                    w2[j] = bf2f(q1[j]); w3[j] = bf2f(q1[j + 4]);
                }
                __builtin_nontemporal_store(w0, (f32x4*)(arow + mP + kc));
                __builtin_nontemporal_store(w1, (f32x4*)(arow + mP + kc + 4));
                __builtin_nontemporal_store(w2, (f32x4*)(arow + mP + 32 + kc));
                __builtin_nontemporal_store(w3, (f32x4*)(arow + mP + 32 + kc + 4));
            }
            block_sync_lds();
        }
        // tail: consume step 63 (ps[1]) with vA loaded at st=63
        {
            const int pb = 1, mP = 63 * 64;
            s16x8 pf[4];
            #pragma unroll
            for (int nt = 0; nt < 4; ++nt)
                pf[nt] = *(const s16x8*)&ps[pb][pswz(nt * 16 + r, kc)];
            #pragma unroll
            for (int nt = 0; nt < 4; ++nt) {
                acc[0][nt] = MFMA16(vA00, pf[nt], acc[0][nt]);
                acc[1][nt] = MFMA16(vA01, pf[nt], acc[1][nt]);
            }
            #pragma unroll
            for (int nt = 0; nt < 4; ++nt)
                pf[nt] = *(const s16x8*)&ps[pb][pswz(nt * 16 + r, 32 + kc)];
            #pragma unroll
            for (int nt = 0; nt < 4; ++nt) {
                acc[0][nt] = MFMA16(vA10, pf[nt], acc[0][nt]);
                acc[1][nt] = MFMA16(vA11, pf[nt], acc[1][nt]);
            }
            if (wact) {
                s16x8 q0 = *(const s16x8*)&ps[pb][pswz(ntw * 16 + r, kc)];
                s16x8 q1 = *(const s16x8*)&ps[pb][pswz(ntw * 16 + r, 32 + kc)];
                f32x4 w0, w1, w2, w3;
                #pragma unroll
                for (int j = 0; j < 4; ++j) {
                    w0[j] = bf2f(q0[j]); w1[j] = bf2f(q0[j + 4]);
                    w2[j] = bf2f(q1[j]); w3[j] = bf2f(q1[j + 4]);
                }
                __builtin_nontemporal_store(w0, (f32x4*)(arow + mP + kc));
                __builtin_nontemporal_store(w1, (f32x4*)(arow + mP + kc + 4));
                __builtin_nontemporal_store(w2, (f32x4*)(arow + mP + 32 + kc));
                __builtin_nontemporal_store(w3, (f32x4*)(arow + mP + 32 + kc + 4));
            }
        }
        // epilogue: out = gamma*acc + x
        const float gm = gamma[0];
        #pragma unroll
        for (int ct = 0; ct < 2; ++ct) {
            #pragma unroll
            for (int nt = 0; nt < 4; ++nt) {
                #pragma unroll
                for (int j = 0; j < 4; ++j) {
                    int c = cw + ct * 16 + hi * 4 + j;
                    size_t idx = ((size_t)b * NC + c) * NN + n0 + nt * 16 + r;
                    out[idx] = gm * acc[ct][nt][j] + x[idx];
                }
            }
        }
    }
}

extern "C" void kernel_launch(void* const* d_in, const int* in_sizes, int n_in,
                              void* d_out, int out_size, void* d_ws, size_t ws_size,
                              hipStream_t stream) {
    const float* x     = (const float*)d_in[0];
    const float* Wq    = (const float*)d_in[1];
    const float* bq    = (const float*)d_in[2];
    const float* Wk    = (const float*)d_in[3];
    const float* bk    = (const float*)d_in[4];
    const float* Wv    = (const float*)d_in[5];
    const float* bv    = (const float*)d_in[6];
    const float* gamma = (const float*)d_in[7];

    float* out = (float*)d_out;
    float* att = out + (size_t)NB * NC * NN;   // attention output region (268 MB)

    // workspace: qh | ql | kh | kl (each B*N*32 bf16 = 1 MB) | v bf16 (8 MB)
    const size_t qk_elems = (size_t)NB * NN * NQ;
    __hip_bfloat16* qh = (__hip_bfloat16*)d_ws;
    __hip_bfloat16* ql = qh + qk_elems;
    __hip_bfloat16* kh = ql + qk_elems;
    __hip_bfloat16* kl = kh + qk_elems;
    __hip_bfloat16* vo = kl + qk_elems;

    k_proj <<<dim3(NN / 64, NB), 512, 0, stream>>>(x, Wq, bq, Wk, bk, Wv, bv,
                                                   qh, ql, kh, kl, vo);
    k_fused<<<dim3(256), 1024, 0, stream>>>(qh, ql, kh, kl, vo,
                                            x, gamma, out, att);
}